// Round 8
// baseline (244.041 us; speedup 1.0000x reference)
//
#include <hip/hip_runtime.h>
#include <hip/hip_bf16.h>

// Problem constants
#define B_  2
#define L_  512
#define D_  768
#define H_  12
#define E_  32
#define M_  4
#define P_  256
#define EMB_ 768
#define BS_ 64
#define C_  97
#define N_  (B_*P_)   // 512

#define KTOT_    49152      // EMB*BS
#define CPAD_    112        // 97 padded to 7*16
#define KSPLIT_  48
#define KCHUNK_  (KTOT_/KSPLIT_)   // 1024, 16 ks-steps of 64; divides 4096 -> no group crossing
#define PSTR_    128        // partial chunk stride (floats): 512 B, cache-line exclusive
#define TILE_    (CPAD_*64) // 7168 ushorts = 14336 B per k-step tile of WBt

typedef __hip_bfloat16 bf16;
typedef __attribute__((ext_vector_type(8))) short bf16x8;
typedef __attribute__((ext_vector_type(4))) float f32x4;
typedef __attribute__((ext_vector_type(8))) float f32x8;

__device__ inline float ldIn(const void* p, long idx, int isbf) {
    return isbf ? (float)((const bf16*)p)[idx] : ((const float*)p)[idx];
}

__device__ inline unsigned short f2bf(float f) {
    bf16 h = (bf16)f;
    return *(unsigned short*)&h;
}

__device__ inline float bf2f(unsigned short u) {
    bf16 h = *(bf16*)&u;
    return (float)h;
}

// ---------------- K0: dtype detection + c23 zero-init ----------------
__global__ void dtype_detect(const void* __restrict__ seq, int* __restrict__ flag,
                             float* __restrict__ c23) {
    __shared__ int cnt;
    if (threadIdx.x == 0) cnt = 0;
    if (threadIdx.x < 2*C_) c23[threadIdx.x] = 0.f;
    __syncthreads();
    const unsigned short* u = (const unsigned short*)seq;
    int bad = 0;
    for (int i = threadIdx.x; i < 1024; i += 256) {
        unsigned short e = (u[i] >> 7) & 0xFF;
        if (e >= 140) bad++;
    }
    atomicAdd(&cnt, bad);
    __syncthreads();
    if (threadIdx.x == 0) flag[0] = (cnt < 16) ? 1 : 0;   // 1 = bf16 inputs
}

// ---------------- prep (z-reordered): z=0 c23 (96 blocks), z=1 W_rel conv,
// z=2..9 transposes, z=10 W_bil->f32.
struct PrepArgs {
    const void* src[8];
    long off[8];
    int K[8];
    int Ncols[8];
    int Npad[8];
    unsigned short* dst[8];
    const void* W_bil;  float* W_bilF;
    const void* b_f; const void* W_unet; const void* b_unet;
    const void* W_mlp; const void* b_mlp; float* c23;
    const void* W_rel; unsigned short* WBt;
};

union PrepSm {
    float T[32][65];                 // 8320 B
    unsigned short TW[CPAD_][72];    // 16128 B
};

__global__ void prep_kernel(PrepArgs a, const int* __restrict__ dtf) {
    int isbf = dtf[0];
    int z = blockIdx.z;
    __shared__ PrepSm sm;
    int tid = threadIdx.x;
    if (z == 0) {
        // c23 partial: 96 blocks x 8 d-rows, coalesced over c, atomic accumulate
        int lin = blockIdx.y*48 + blockIdx.x;
        if (lin >= 96) return;
        int c = tid;
        if (c >= C_) return;
        float s2 = 0.f, s3 = 0.f;
        int d0 = lin*8;
        for (int i = 0; i < 8; i++) {
            int d = d0 + i;
            float bf = ldIn(a.b_f, d, isbf);
            s2 += bf * ldIn(a.W_unet, (long)d*C_ + c, isbf);
            s3 += bf * ldIn(a.W_mlp,  (long)d*C_ + c, isbf);
        }
        if (lin == 0) {
            s2 += ldIn(a.b_unet, c, isbf);
            s3 += ldIn(a.b_mlp,  c, isbf);
        }
        atomicAdd(&a.c23[c], s2);
        atomicAdd(&a.c23[C_ + c], s3);
    } else if (z == 1) {
        // W_rel -> WBt TILED: [kstep][c][64] bf16, c padded to 112.
        int lin = blockIdx.y*48 + blockIdx.x;
        if (lin >= KTOT_/64) return;
        int k0 = lin * 64;
        for (int idx = tid; idx < 64*97; idx += 256) {
            int kk = idx / 97, c = idx % 97;
            sm.TW[c][kk] = f2bf(ldIn(a.W_rel, (long)(k0+kk)*C_ + c, isbf));
        }
        for (int idx = tid; idx < 15*64; idx += 256) {
            sm.TW[97 + (idx>>6)][idx & 63] = 0;
        }
        __syncthreads();
        unsigned short* tb = a.WBt + (long)lin*TILE_;
        for (int t = 0; t < 4; t++) {
            int idx = tid + t*256;      // < 896 = 112*8
            if (idx < 896) {
                int c = idx >> 3, kc = idx & 7;
                *(uint4*)(tb + idx*8) = *(uint4*)&sm.TW[c][kc*8];
            }
        }
    } else if (z <= 9) {
        int j = z - 2;
        int K = a.K[j], Ncols = a.Ncols[j], Npad = a.Npad[j];
        int k0 = blockIdx.x*32, n0 = blockIdx.y*64;
        if (k0 >= K || n0 >= Npad) return;
        const void* src = a.src[j];
        long off = a.off[j];
        unsigned short* dst = a.dst[j];
        // read: 64 consecutive cols per row (coalesced 128/256 B)
        int c64 = tid & 63, r4 = tid >> 6;
        for (int p = 0; p < 8; p++) {
            int r = r4 + p*4;
            int n = n0 + c64;
            sm.T[r][c64] = (n < Ncols) ? ldIn(src, off + (long)(k0+r)*Ncols + n, isbf) : 0.f;
        }
        __syncthreads();
        // write: 32 consecutive k per n (coalesced)
        int cc = tid & 31, n8 = tid >> 5;
        for (int p = 0; p < 8; p++) {
            int nn = n8 + p*8;
            dst[(long)(n0+nn)*K + k0 + cc] = f2bf(sm.T[cc][nn]);
        }
    } else {
        int lin = blockIdx.y*48 + blockIdx.x;
        int idx = lin*256 + tid;
        if (idx < 291*C_) a.W_bilF[idx] = ldIn(a.W_bil, idx, isbf);
    }
}

// ---------------- gather: bx<768 entatt, else ment ----------------
__global__ void gather_kernel(const void* __restrict__ seq, const void* __restrict__ attn,
                              const int* __restrict__ entity_pos,
                              unsigned short* __restrict__ mentb, float* __restrict__ ent_emb,
                              float* __restrict__ ent_att, const int* __restrict__ dtf) {
    int isbf = dtf[0];
    if (blockIdx.x < 768) {
        int beh = blockIdx.x;
        int h = beh % H_;
        int be = beh / H_;
        int b = be >> 5;
        int pos[M_];
        for (int m = 0; m < M_; m++) pos[m] = entity_pos[be*M_+m] + 1;
        for (int l = threadIdx.x; l < L_; l += 256) {
            float s = 0.f;
            for (int m = 0; m < M_; m++)
                s += ldIn(attn, (((long)(b*H_ + h))*L_ + pos[m])*L_ + l, isbf);
            ent_att[(long)beh*L_ + l] = 0.25f * s;
        }
    } else {
        int be = blockIdx.x - 768;     // 0..63
        int b = be >> 5;
        int pos[M_];
        for (int m = 0; m < M_; m++) pos[m] = entity_pos[be*M_+m] + 1;
        for (int d = threadIdx.x; d < D_; d += 256) {
            float x[M_];
            for (int m = 0; m < M_; m++) {
                x[m] = ldIn(seq, ((long)b*L_ + pos[m])*D_ + d, isbf);
                mentb[((long)be*M_ + m)*D_ + d] = f2bf(x[m]);
            }
            float mx = fmaxf(fmaxf(x[0],x[1]), fmaxf(x[2],x[3]));
            float s = expf(x[0]-mx)+expf(x[1]-mx)+expf(x[2]-mx)+expf(x[3]-mx);
            ent_emb[(long)be*D_ + d] = mx + logf(s);
        }
    }
}

// ---------------- K3: ht_att (bf16) = normalize_L( mean_H(ha*ta) ) ----------------
__global__ void htatt_kernel(const float* __restrict__ ent_att, const int* __restrict__ hts,
                             unsigned short* __restrict__ htb) {
    int bp = blockIdx.x;            // 512 blocks
    int b = bp >> 8;
    int h_e = hts[bp*2+0], t_e = hts[bp*2+1];
    const float* ea_h = ent_att + (long)((b*E_ + h_e)*H_)*L_;
    const float* ea_t = ent_att + (long)((b*E_ + t_e)*H_)*L_;
    __shared__ float red[256];
    float v[2];
    for (int t = 0; t < 2; t++) {
        int l = threadIdx.x + t*256;
        float s = 0.f;
        for (int h = 0; h < H_; h++) s += ea_h[h*L_+l] * ea_t[h*L_+l];
        v[t] = s * (1.0f/H_);
    }
    red[threadIdx.x] = v[0] + v[1];
    __syncthreads();
    for (int off = 128; off > 0; off >>= 1) {
        if (threadIdx.x < off) red[threadIdx.x] += red[threadIdx.x+off];
        __syncthreads();
    }
    float inv = 1.0f / (red[0] + 1e-5f);
    for (int t = 0; t < 2; t++) {
        int l = threadIdx.x + t*256;
        htb[(long)bp*L_ + l] = f2bf(v[t] * inv);
    }
}

// ---------------- catb: hcatb=[hs,rs], tcatb=[ts,rs] in bf16 ----------------
__global__ void catb_kernel(const float* __restrict__ ent_emb, const float* __restrict__ rs,
                            const int* __restrict__ hts,
                            unsigned short* __restrict__ hcatb, unsigned short* __restrict__ tcatb) {
    int n = blockIdx.x;             // 512
    int b = n >> 8;
    int h_e = hts[n*2+0], t_e = hts[n*2+1];
    const float* eh = ent_emb + (long)(b*E_ + h_e)*D_;
    const float* et = ent_emb + (long)(b*E_ + t_e)*D_;
    const float* r  = rs + (long)n*D_;
    for (int k = threadIdx.x; k < D_; k += 256) {
        hcatb[(long)n*1536 + k] = f2bf(eh[k]);
        tcatb[(long)n*1536 + k] = f2bf(et[k]);
        unsigned short rb = f2bf(r[k]);
        hcatb[(long)n*1536 + 768 + k] = rb;
        tcatb[(long)n*1536 + 768 + k] = rb;
    }
}

// ---------------- Generic MFMA GEMM (double-buffered), 32x32 tiles ----------------
struct MfmaJob {
    const unsigned short* A[4];
    const unsigned short* Bt[4];
    const void* bias[4];
    void* C[4];
    int K[4];
    int ldc[4];
    int act[4];
    int obf[4];
};

__global__ void mfma_nt2_kernel(MfmaJob args, const int* __restrict__ dtf) {
    int z = blockIdx.z;
    const unsigned short* A  = args.A[z];
    const unsigned short* Bt = args.Bt[z];
    const void* bias = args.bias[z];
    void* C = args.C[z];
    int K = args.K[z], ldc = args.ldc[z], act = args.act[z], obf = args.obf[z];
    __shared__ unsigned short Al[2][32][72];
    __shared__ unsigned short Btl[2][32][72];
    int m0 = blockIdx.x*32, n0 = blockIdx.y*32;
    int tid = threadIdx.x, wave = tid>>6, lane = tid&63;
    int lm = lane&15, lq = lane>>4;
    int rowg = wave>>1, cgrp = wave&1;   // wave -> (row half, col half)
    int rr = tid >> 3;                // 0..31
    int kc = (tid & 7) * 8;           // col offset in ushorts
    uint4 ra, rb;

    ra = *(const uint4*)(A  + (long)(m0+rr)*K + kc);
    rb = *(const uint4*)(Bt + (long)(n0+rr)*K + kc);
    *(uint4*)&Al[0][rr][kc]  = ra;
    *(uint4*)&Btl[0][rr][kc] = rb;

    int nst = K >> 6;
    f32x4 acc = {};
    for (int ks = 0; ks < nst; ks++) {
        __syncthreads();
        if (ks+1 < nst) {
            int k0 = (ks+1) << 6;
            ra = *(const uint4*)(A  + (long)(m0+rr)*K + k0 + kc);
            rb = *(const uint4*)(Bt + (long)(n0+rr)*K + k0 + kc);
        }
        int cb = ks & 1;
        #pragma unroll
        for (int half = 0; half < 2; half++) {
            bf16x8 af  = *(bf16x8*)&Al[cb][rowg*16+lm][half*32+lq*8];
            bf16x8 bfr = *(bf16x8*)&Btl[cb][cgrp*16+lm][half*32+lq*8];
            acc = __builtin_amdgcn_mfma_f32_16x16x32_bf16(af, bfr, acc, 0, 0, 0);
        }
        if (ks+1 < nst) {
            int nb = (ks+1) & 1;
            *(uint4*)&Al[nb][rr][kc]  = ra;
            *(uint4*)&Btl[nb][rr][kc] = rb;
        }
    }
    int isbf = dtf[0];
    int n = n0 + cgrp*16 + lm;
    float bia = bias ? ldIn(bias, n, isbf) : 0.f;
    #pragma unroll
    for (int r = 0; r < 4; r++) {
        int m = m0 + rowg*16 + lq*4 + r;
        float v = acc[r] + bia;
        if (act == 1) v = tanhf(v);
        if (obf) ((unsigned short*)C)[(long)m*ldc + n] = f2bf(v);
        else     ((float*)C)[(long)m*ldc + n] = v;
    }
}

// ================= r1 via MFMA =================
// v7: NO LDS staging for W, NO barriers in the K-loop. The per-step
// global->LDS->vmcnt(0)->barrier drain was the invariant ~3700-cyc/step cost
// that survived v0..v6 (41 us across 3 different structures). Same-kz blocks
// land on one XCD (48%8==0), so the 229-KB WBt chunk is L2-resident; each
// lane reads its B-fragments DIRECTLY from L2 with global_load_dwordx4,
// register-double-buffered (prefetch ks+1 while MFMAs of ks run). Waves run
// free: latency hidden by 3 waves/SIMD + reg pipeline.
// Grid (48,16)=768 blocks x 256 thr; LDS = 2.2 KB (hz tile only).
__global__ __launch_bounds__(256, 3)
void r1_mfma_kernel(const float* __restrict__ hz, const float* __restrict__ tz,
                    const unsigned short* __restrict__ WBt,
                    float* __restrict__ partial) {
    __shared__ float hzL[32][17];
    int kz = blockIdx.x;
    int nb0 = blockIdx.y * 32;
    int gk0 = kz * 16;               // global k-step base
    int gi0 = kz * 16;               // hz col base
    int g0 = (kz * KCHUNK_) >> 12;   // tz group, fixed for the whole chunk
    int tid = threadIdx.x;
    int wave = tid >> 6, lane = tid & 63;
    int lm = lane & 15, lq = lane >> 4;
    int rowg = wave >> 1;            // 0..1  (16-row group)
    int cgrp = wave & 1;             // 0 -> c-tiles 0..3, 1 -> c-tiles 4..6
    int nct = 4 - cgrp;
    int nrow = nb0 + rowg*16 + lm;

    // hz tile 32 rows x 16 cols -> LDS (512 floats, 1 float2 per thread)
    {
        int r = tid >> 3, q = (tid & 7) * 2;
        float2 v = *(const float2*)(hz + (long)(nb0 + r)*EMB_ + gi0 + q);
        hzL[r][q] = v.x; hzL[r][q+1] = v.y;
    }
    // tz fragment for this lane's row, f32 in registers (16 VGPR)
    f32x8 t0, t1;
    {
        const float* tp = tz + (long)nrow*EMB_ + g0*64;
        float4 x0 = *(const float4*)(tp + lq*8);
        float4 y0 = *(const float4*)(tp + lq*8 + 4);
        float4 x1 = *(const float4*)(tp + 32 + lq*8);
        float4 y1 = *(const float4*)(tp + 32 + lq*8 + 4);
        t0[0]=x0.x; t0[1]=x0.y; t0[2]=x0.z; t0[3]=x0.w;
        t0[4]=y0.x; t0[5]=y0.y; t0[6]=y0.z; t0[7]=y0.w;
        t1[0]=x1.x; t1[1]=x1.y; t1[2]=x1.z; t1[3]=x1.w;
        t1[4]=y1.x; t1[5]=y1.y; t1[6]=y1.z; t1[7]=y1.w;
    }
    __syncthreads();   // hzL ready; ONLY barrier in the kernel

    // per-lane W-fragment base: c = (cgrp*4)*16 + lm row, k-offset lq*8
    const unsigned short* wb = WBt + (long)gk0*TILE_ + (cgrp*64 + lm)*64 + lq*8;
    // c-tile stride: 16 rows * 64 = 1024 ushorts; half stride: 32 ushorts.

    f32x4 acc[4] = {};
    // prologue: load B-frags for ks=0 into current regs
    bf16x8 cb0[4], cb1[4];
    #pragma unroll
    for (int ct = 0; ct < 4; ct++) {
        if (ct < nct) {
            cb0[ct] = *(const bf16x8*)(wb + ct*1024);
            cb1[ct] = *(const bf16x8*)(wb + ct*1024 + 32);
        }
    }
    #pragma unroll 2
    for (int ks = 0; ks < KCHUNK_/64; ks++) {
        // prefetch next step's B-frags (independent of this step's MFMAs)
        bf16x8 nb0r[4], nb1r[4];
        if (ks+1 < KCHUNK_/64) {
            const unsigned short* wn = wb + (long)(ks+1)*TILE_;
            #pragma unroll
            for (int ct = 0; ct < 4; ct++) {
                if (ct < nct) {
                    nb0r[ct] = *(const bf16x8*)(wn + ct*1024);
                    nb1r[ct] = *(const bf16x8*)(wn + ct*1024 + 32);
                }
            }
        }
        float hvk = hzL[rowg*16 + lm][ks];
        unsigned short oa0[8], oa1[8];
        #pragma unroll
        for (int e = 0; e < 8; e++) {
            oa0[e] = f2bf(t0[e] * hvk);
            oa1[e] = f2bf(t1[e] * hvk);
        }
        bf16x8 a0 = *(bf16x8*)oa0;
        bf16x8 a1 = *(bf16x8*)oa1;
        #pragma unroll
        for (int ct = 0; ct < 4; ct++) {
            if (ct < nct) {
                acc[ct] = __builtin_amdgcn_mfma_f32_16x16x32_bf16(a0, cb0[ct], acc[ct], 0, 0, 0);
                acc[ct] = __builtin_amdgcn_mfma_f32_16x16x32_bf16(a1, cb1[ct], acc[ct], 0, 0, 0);
            }
        }
        if (ks+1 < KCHUNK_/64) {
            #pragma unroll
            for (int ct = 0; ct < 4; ct++) {
                if (ct < nct) { cb0[ct] = nb0r[ct]; cb1[ct] = nb1r[ct]; }
            }
        }
    }
    // epilogue: write ALL 4 c-tiles per wave (c 0..127) so every 512-B chunk
    // is fully written -> no partial-sector RMW. acc[3] of cgrp=1 is zero.
    #pragma unroll
    for (int ct = 0; ct < 4; ct++) {
        int c = (cgrp*4 + ct)*16 + lm;
        #pragma unroll
        for (int r = 0; r < 4; r++) {
            int nl = rowg*16 + lq*4 + r;
            partial[((long)(nb0+nl)*KSPLIT_ + kz)*PSTR_ + c] = acc[ct][r];
        }
    }
}

// ---------------- fused: r1 streaming reduce + r2/r3 LSE + final projection ----------------
__global__ void r23out_kernel(const float* __restrict__ partial, const void* __restrict__ b_rel,
                              const float* __restrict__ mu, const float* __restrict__ c23,
                              const int* __restrict__ hts, const int* __restrict__ mention_idx,
                              const float* __restrict__ W_bilF, const void* __restrict__ b_bil,
                              void* __restrict__ out, const int* __restrict__ dtf) {
    int bp = blockIdx.x;
    int b = bp >> 8;
    int c = threadIdx.x;
    int isbf = dtf[0];
    __shared__ float row[292];
    if (c < C_) {
        const float* pr = partial + (long)bp*KSPLIT_*PSTR_;
        float r1v = 0.f;
        #pragma unroll 8
        for (int kz = 0; kz < KSPLIT_; kz++)
            r1v += pr[kz*PSTR_ + c];
        r1v += ldIn(b_rel, c, isbf);
        int h_e = hts[bp*2+0], t_e = hts[bp*2+1];
        const float* mu2h = mu;
        const float* mu2t = mu + 32768;
        const float* mu3h = mu + 65536;
        const float* mu3t = mu + 98304;
        float ah2[4], at2[4], ah3[4], at3[4];
        for (int m = 0; m < 4; m++) {
            int emh = mention_idx[(b*E_ + h_e)*M_ + m];
            int emt = mention_idx[(b*E_ + t_e)*M_ + m];
            ah2[m] = mu2h[(long)(b*128 + emh)*128 + c];
            ah3[m] = mu3h[(long)(b*128 + emh)*128 + c];
            at2[m] = mu2t[(long)(b*128 + emt)*128 + c];
            at3[m] = mu3t[(long)(b*128 + emt)*128 + c];
        }
        float c2 = c23[c], c3 = c23[C_ + c];
        float v2[16], v3[16];
        int q = 0;
        for (int i = 0; i < 4; i++) {
            for (int j = 0; j < 4; j++, q++) {
                float x2 = ah2[i] + at2[j] + c2;
                v2[q] = tanhf(x2);
                float x3 = ah3[i] + at3[j] + c3;
                float t = tanhf(0.7978845608028654f * (x3 + 0.044715f*x3*x3*x3));
                v3[q] = 0.5f * x3 * (1.0f + t);
            }
        }
        float m2 = v2[0], m3 = v3[0];
        for (q = 1; q < 16; q++) { m2 = fmaxf(m2, v2[q]); m3 = fmaxf(m3, v3[q]); }
        float s2 = 0.f, s3 = 0.f;
        for (q = 0; q < 16; q++) { s2 += expf(v2[q]-m2); s3 += expf(v3[q]-m3); }
        row[c]        = r1v;
        row[C_ + c]   = m2 + logf(s2);
        row[2*C_ + c] = m3 + logf(s3);
    }
    __syncthreads();
    if (c >= C_) return;
    float a0 = 0.f, a1 = 0.f, a2 = 0.f, a3 = 0.f;
    #pragma unroll 4
    for (int k = 0; k < 288; k += 4) {
        a0 += row[k+0] * W_bilF[(k+0)*C_ + c];
        a1 += row[k+1] * W_bilF[(k+1)*C_ + c];
        a2 += row[k+2] * W_bilF[(k+2)*C_ + c];
        a3 += row[k+3] * W_bilF[(k+3)*C_ + c];
    }
    a0 += row[288] * W_bilF[288*C_ + c];
    a1 += row[289] * W_bilF[289*C_ + c];
    a2 += row[290] * W_bilF[290*C_ + c];
    float v = a0 + a1 + a2 + a3 + ldIn(b_bil, c, isbf);
    if (isbf) ((bf16*)out)[(long)bp*C_ + c] = (bf16)v;
    else      ((float*)out)[(long)bp*C_ + c] = v;
}

extern "C" void kernel_launch(void* const* d_in, const int* in_sizes, int n_in,
                              void* d_out, int out_size, void* d_ws, size_t ws_size,
                              hipStream_t stream) {
    const void* seq        = d_in[0];
    const void* attn       = d_in[1];
    const int*  entity_pos = (const int*)d_in[2];
    const int*  hts        = (const int*)d_in[3];
    const int*  mention_idx= (const int*)d_in[4];
    const void* W_head     = d_in[5];
    const void* b_head     = d_in[6];
    const void* W_tail     = d_in[7];
    const void* b_tail     = d_in[8];
    const void* W_rel      = d_in[9];
    const void* b_rel      = d_in[10];
    const void* W_fh       = d_in[11];
    const void* W_ft       = d_in[12];
    const void* b_f        = d_in[13];
    const void* W_unet     = d_in[14];
    const void* b_unet     = d_in[15];
    const void* W_mlp      = d_in[16];
    const void* b_mlp      = d_in[17];
    const void* W_bil      = d_in[18];
    const void* b_bil      = d_in[19];

    float* w = (float*)d_ws;
    int*   dtf      = (int*)w;                               // 64
    unsigned short* mentb = (unsigned short*)(w + 64);       // 98304 fl
    float* ent_emb  = w + 98368;                             // 49152
    float* ent_att  = w + 147520;                            // 393216
    unsigned short* htb = (unsigned short*)(w + 540736);     // 131072 fl
    float* rs       = w + 671808;                            // 393216
    float* hz       = w + 1065024;                           // 393216
    float* tz       = w + 1458240;                           // 393216
    float* mu       = w + 1851456;                           // 131072
    float* c23      = w + 1982528;                           // 256
    unsigned short* seqT  = (unsigned short*)(w + 1982784);  // 393216 fl
    unsigned short* WhT   = (unsigned short*)(w + 2376000);  // 589824 fl
    unsigned short* WtT   = (unsigned short*)(w + 2965824);  // 589824 fl
    unsigned short* WfhT  = (unsigned short*)(w + 3555648);  // 294912 fl
    unsigned short* WftT  = (unsigned short*)(w + 3850560);  // 294912 fl
    unsigned short* WunetT= (unsigned short*)(w + 4145472);  // 49152 fl
    unsigned short* WmlpT = (unsigned short*)(w + 4194624);  // 49152 fl
    unsigned short* Tbh   = (unsigned short*)(w + 4243776);  // 98304 fl
    unsigned short* Tbt   = (unsigned short*)(w + 4342080);  // 98304 fl
    unsigned short* hcatb = (unsigned short*)(w + 4440384);  // 393216 fl
    unsigned short* tcatb = (unsigned short*)(w + 4833600);  // 393216 fl
    unsigned short* WBt   = (unsigned short*)(w + 5226816);  // 2752512 fl (tiled: 768*7168 ushorts, exact fit)
    float* partial  = w + 7979328;                           // 3670016 fl (used: 512*48*128 = 3145728)
    float* W_bilF   = w + 11649344;                          // 28227 fl

    // 0. dtype detection + c23 init
    dtype_detect<<<1, 256, 0, stream>>>(seq, dtf, c23);
    // 1. prep: c23 (z=0) + W_rel conv (z=1) + transposes (z=2..9) + W_bilF (z=10)
    {
        PrepArgs a = {};
        const void* srcs[8] = {W_head, W_tail, W_fh, W_ft, W_unet, W_mlp, seq, seq};
        long offs[8]   = {0,0,0,0,0,0,0,393216};
        int Ks[8]      = {1536,1536,768,768,768,768,512,512};
        int Ncols8[8]  = {768,768,768,768,97,97,768,768};
        int Npads[8]   = {768,768,768,768,128,128,768,768};
        unsigned short* dsts[8] = {WhT, WtT, WfhT, WftT, WunetT, WmlpT, seqT, seqT+393216};
        for (int z = 0; z < 8; z++) {
            a.src[z]=srcs[z]; a.off[z]=offs[z]; a.K[z]=Ks[z];
            a.Ncols[z]=Ncols8[z]; a.Npad[z]=Npads[z]; a.dst[z]=dsts[z];
        }
        a.W_bil = W_bil; a.W_bilF = W_bilF;
        a.b_f = b_f; a.W_unet = W_unet; a.b_unet = b_unet;
        a.W_mlp = W_mlp; a.b_mlp = b_mlp; a.c23 = c23;
        a.W_rel = W_rel; a.WBt = WBt;
        prep_kernel<<<dim3(48, 16, 11), 256, 0, stream>>>(a, dtf);
    }
    // 2. gather: entatt + ment
    gather_kernel<<<768 + 64, 256, 0, stream>>>(seq, attn, entity_pos, mentb, ent_emb, ent_att, dtf);
    // 3. ht attention (normalized, bf16)
    htatt_kernel<<<N_, 256, 0, stream>>>(ent_att, hts, htb);
    // 4. gemmA: rs (z=0,1) + T_{h,t} (z=2,3)  [32x32 tiles]
    {
        MfmaJob ga = {};
        for (int z = 0; z < 2; z++) {
            ga.A[z] = htb + (long)z*256*512; ga.Bt[z] = seqT + (long)z*393216;
            ga.bias[z] = nullptr; ga.C[z] = rs + (long)z*256*768;
            ga.K[z] = 512; ga.ldc[z] = 768; ga.act[z] = 0; ga.obf[z] = 0;
        }
        ga.A[2] = mentb; ga.Bt[2] = WfhT; ga.bias[2] = nullptr; ga.C[2] = Tbh;
        ga.K[2] = 768; ga.ldc[2] = 768; ga.act[2] = 0; ga.obf[2] = 1;
        ga.A[3] = mentb; ga.Bt[3] = WftT; ga.bias[3] = nullptr; ga.C[3] = Tbt;
        ga.K[3] = 768; ga.ldc[3] = 768; ga.act[3] = 0; ga.obf[3] = 1;
        mfma_nt2_kernel<<<dim3(8, 24, 4), 256, 0, stream>>>(ga, dtf);
    }
    // 5. concatenated inputs (bf16)
    catb_kernel<<<N_, 256, 0, stream>>>(ent_emb, rs, hts, hcatb, tcatb);
    // 6. gemmB: hz/tz = tanh(cat @ W + b)
    {
        MfmaJob ga = {};
        ga.A[0] = hcatb; ga.Bt[0] = WhT; ga.bias[0] = b_head; ga.C[0] = hz;
        ga.A[1] = tcatb; ga.Bt[1] = WtT; ga.bias[1] = b_tail; ga.C[1] = tz;
        for (int z = 0; z < 2; z++) { ga.K[z] = 1536; ga.ldc[z] = 768; ga.act[z] = 1; ga.obf[z] = 0; }
        mfma_nt2_kernel<<<dim3(16, 24, 2), 256, 0, stream>>>(ga, dtf);
    }
    // 7. gemmC: mu_q = T @ W_{unet,mlp}
    {
        MfmaJob ga = {};
        const unsigned short* As[4] = {Tbh, Tbt, Tbh, Tbt};
        const unsigned short* Bs[4] = {WunetT, WunetT, WmlpT, WmlpT};
        for (int q = 0; q < 4; q++) {
            ga.A[q] = As[q]; ga.Bt[q] = Bs[q]; ga.bias[q] = nullptr;
            ga.C[q] = mu + q*32768;
            ga.K[q] = 768; ga.ldc[q] = 128; ga.act[q] = 0; ga.obf[q] = 0;
        }
        mfma_nt2_kernel<<<dim3(8, 4, 4), 256, 0, stream>>>(ga, dtf);
    }
    // 8. r1 partials via MFMA (barrier-free K-loop, L2-direct B-frags)
    r1_mfma_kernel<<<dim3(KSPLIT_, 16), 256, 0, stream>>>(hz, tz, WBt, partial);
    // 9. fused reduce + r2/r3 + final projection
    r23out_kernel<<<N_, 128, 0, stream>>>(partial, b_rel, mu, c23, hts, mention_idx,
                                          W_bilF, b_bil, d_out, dtf);
}

// Round 9
// 217.965 us; speedup vs baseline: 1.1196x; 1.1196x over previous
//
#include <hip/hip_runtime.h>
#include <hip/hip_bf16.h>

// Problem constants
#define B_  2
#define L_  512
#define D_  768
#define H_  12
#define E_  32
#define M_  4
#define P_  256
#define EMB_ 768
#define BS_ 64
#define C_  97
#define N_  (B_*P_)   // 512

#define KTOT_    49152      // EMB*BS
#define CPAD_    112        // 97 padded to 7*16
#define KSPLIT_  48
#define KCHUNK_  (KTOT_/KSPLIT_)   // 1024, 16 ks-steps of 64; divides 4096 -> no group crossing
#define PSTR_    128        // partial chunk stride (floats): 512 B, cache-line exclusive
#define TILE_    (CPAD_*64) // 7168 ushorts = 14336 B per k-step tile of WBt (fragment-major)

typedef __hip_bfloat16 bf16;
typedef __attribute__((ext_vector_type(8))) short bf16x8;
typedef __attribute__((ext_vector_type(4))) float f32x4;
typedef __attribute__((ext_vector_type(8))) float f32x8;

__device__ inline float ldIn(const void* p, long idx, int isbf) {
    return isbf ? (float)((const bf16*)p)[idx] : ((const float*)p)[idx];
}

__device__ inline unsigned short f2bf(float f) {
    bf16 h = (bf16)f;
    return *(unsigned short*)&h;
}

__device__ inline float bf2f(unsigned short u) {
    bf16 h = *(bf16*)&u;
    return (float)h;
}

// ---------------- K0: dtype detection + c23 zero-init ----------------
__global__ void dtype_detect(const void* __restrict__ seq, int* __restrict__ flag,
                             float* __restrict__ c23) {
    __shared__ int cnt;
    if (threadIdx.x == 0) cnt = 0;
    if (threadIdx.x < 2*C_) c23[threadIdx.x] = 0.f;
    __syncthreads();
    const unsigned short* u = (const unsigned short*)seq;
    int bad = 0;
    for (int i = threadIdx.x; i < 1024; i += 256) {
        unsigned short e = (u[i] >> 7) & 0xFF;
        if (e >= 140) bad++;
    }
    atomicAdd(&cnt, bad);
    __syncthreads();
    if (threadIdx.x == 0) flag[0] = (cnt < 16) ? 1 : 0;   // 1 = bf16 inputs
}

// ---------------- prep: z=0 c23 (96 blocks), z=1 W_rel conv (fragment-major),
// z=2..9 transposes, z=10 W_bil->f32.
struct PrepArgs {
    const void* src[8];
    long off[8];
    int K[8];
    int Ncols[8];
    int Npad[8];
    unsigned short* dst[8];
    const void* W_bil;  float* W_bilF;
    const void* b_f; const void* W_unet; const void* b_unet;
    const void* W_mlp; const void* b_mlp; float* c23;
    const void* W_rel; unsigned short* WBt;
};

union PrepSm {
    float T[32][65];                 // 8320 B
    unsigned short TW[CPAD_][72];    // 16128 B
};

__global__ void prep_kernel(PrepArgs a, const int* __restrict__ dtf) {
    int isbf = dtf[0];
    int z = blockIdx.z;
    __shared__ PrepSm sm;
    int tid = threadIdx.x;
    if (z == 0) {
        // c23 partial: 96 blocks x 8 d-rows, coalesced over c, atomic accumulate
        int lin = blockIdx.y*48 + blockIdx.x;
        if (lin >= 96) return;
        int c = tid;
        if (c >= C_) return;
        float s2 = 0.f, s3 = 0.f;
        int d0 = lin*8;
        for (int i = 0; i < 8; i++) {
            int d = d0 + i;
            float bf = ldIn(a.b_f, d, isbf);
            s2 += bf * ldIn(a.W_unet, (long)d*C_ + c, isbf);
            s3 += bf * ldIn(a.W_mlp,  (long)d*C_ + c, isbf);
        }
        if (lin == 0) {
            s2 += ldIn(a.b_unet, c, isbf);
            s3 += ldIn(a.b_mlp,  c, isbf);
        }
        atomicAdd(&a.c23[c], s2);
        atomicAdd(&a.c23[C_ + c], s3);
    } else if (z == 1) {
        // W_rel -> WBt FRAGMENT-MAJOR: per k-step tile t, item idx = (ct*2+h)*64+l
        // stores the 8 bf16 that lane l of c-tile ct, k-half h consumes as the
        // MFMA B-operand: W[row = ct*16+(l&15)][k = h*32+(l>>4)*8 .. +8].
        // A wave's B-frag load in r1 becomes 64x16B CONTIGUOUS (8 lines, all
        // useful) vs the old row-strided 16-lines-per-load.
        int lin = blockIdx.y*48 + blockIdx.x;
        if (lin >= KTOT_/64) return;
        int k0 = lin * 64;
        for (int idx = tid; idx < 64*97; idx += 256) {
            int kk = idx / 97, c = idx % 97;
            sm.TW[c][kk] = f2bf(ldIn(a.W_rel, (long)(k0+kk)*C_ + c, isbf));
        }
        for (int idx = tid; idx < 15*64; idx += 256) {
            sm.TW[97 + (idx>>6)][idx & 63] = 0;
        }
        __syncthreads();
        unsigned short* tb = a.WBt + (long)lin*TILE_;
        for (int t = 0; t < 4; t++) {
            int idx = tid + t*256;      // < 896 = 7ct * 2h * 64l
            if (idx < 896) {
                int l  = idx & 63;
                int h  = (idx >> 6) & 1;
                int ct = idx >> 7;
                int row = ct*16 + (l & 15);
                int col = h*32 + (l >> 4)*8;
                *(uint4*)(tb + idx*8) = *(uint4*)&sm.TW[row][col];
            }
        }
    } else if (z <= 9) {
        int j = z - 2;
        int K = a.K[j], Ncols = a.Ncols[j], Npad = a.Npad[j];
        int k0 = blockIdx.x*32, n0 = blockIdx.y*64;
        if (k0 >= K || n0 >= Npad) return;
        const void* src = a.src[j];
        long off = a.off[j];
        unsigned short* dst = a.dst[j];
        // read: 64 consecutive cols per row (coalesced 128/256 B)
        int c64 = tid & 63, r4 = tid >> 6;
        for (int p = 0; p < 8; p++) {
            int r = r4 + p*4;
            int n = n0 + c64;
            sm.T[r][c64] = (n < Ncols) ? ldIn(src, off + (long)(k0+r)*Ncols + n, isbf) : 0.f;
        }
        __syncthreads();
        // write: 32 consecutive k per n (coalesced)
        int cc = tid & 31, n8 = tid >> 5;
        for (int p = 0; p < 8; p++) {
            int nn = n8 + p*8;
            dst[(long)(n0+nn)*K + k0 + cc] = f2bf(sm.T[cc][nn]);
        }
    } else {
        int lin = blockIdx.y*48 + blockIdx.x;
        int idx = lin*256 + tid;
        if (idx < 291*C_) a.W_bilF[idx] = ldIn(a.W_bil, idx, isbf);
    }
}

// ---------------- gather: bx<768 entatt, else ment ----------------
__global__ void gather_kernel(const void* __restrict__ seq, const void* __restrict__ attn,
                              const int* __restrict__ entity_pos,
                              unsigned short* __restrict__ mentb, float* __restrict__ ent_emb,
                              float* __restrict__ ent_att, const int* __restrict__ dtf) {
    int isbf = dtf[0];
    if (blockIdx.x < 768) {
        int beh = blockIdx.x;
        int h = beh % H_;
        int be = beh / H_;
        int b = be >> 5;
        int pos[M_];
        for (int m = 0; m < M_; m++) pos[m] = entity_pos[be*M_+m] + 1;
        for (int l = threadIdx.x; l < L_; l += 256) {
            float s = 0.f;
            for (int m = 0; m < M_; m++)
                s += ldIn(attn, (((long)(b*H_ + h))*L_ + pos[m])*L_ + l, isbf);
            ent_att[(long)beh*L_ + l] = 0.25f * s;
        }
    } else {
        int be = blockIdx.x - 768;     // 0..63
        int b = be >> 5;
        int pos[M_];
        for (int m = 0; m < M_; m++) pos[m] = entity_pos[be*M_+m] + 1;
        for (int d = threadIdx.x; d < D_; d += 256) {
            float x[M_];
            for (int m = 0; m < M_; m++) {
                x[m] = ldIn(seq, ((long)b*L_ + pos[m])*D_ + d, isbf);
                mentb[((long)be*M_ + m)*D_ + d] = f2bf(x[m]);
            }
            float mx = fmaxf(fmaxf(x[0],x[1]), fmaxf(x[2],x[3]));
            float s = expf(x[0]-mx)+expf(x[1]-mx)+expf(x[2]-mx)+expf(x[3]-mx);
            ent_emb[(long)be*D_ + d] = mx + logf(s);
        }
    }
}

// ---------------- K3: ht_att (bf16) = normalize_L( mean_H(ha*ta) ) ----------------
__global__ void htatt_kernel(const float* __restrict__ ent_att, const int* __restrict__ hts,
                             unsigned short* __restrict__ htb) {
    int bp = blockIdx.x;            // 512 blocks
    int b = bp >> 8;
    int h_e = hts[bp*2+0], t_e = hts[bp*2+1];
    const float* ea_h = ent_att + (long)((b*E_ + h_e)*H_)*L_;
    const float* ea_t = ent_att + (long)((b*E_ + t_e)*H_)*L_;
    __shared__ float red[256];
    float v[2];
    for (int t = 0; t < 2; t++) {
        int l = threadIdx.x + t*256;
        float s = 0.f;
        for (int h = 0; h < H_; h++) s += ea_h[h*L_+l] * ea_t[h*L_+l];
        v[t] = s * (1.0f/H_);
    }
    red[threadIdx.x] = v[0] + v[1];
    __syncthreads();
    for (int off = 128; off > 0; off >>= 1) {
        if (threadIdx.x < off) red[threadIdx.x] += red[threadIdx.x+off];
        __syncthreads();
    }
    float inv = 1.0f / (red[0] + 1e-5f);
    for (int t = 0; t < 2; t++) {
        int l = threadIdx.x + t*256;
        htb[(long)bp*L_ + l] = f2bf(v[t] * inv);
    }
}

// ---------------- catb: hcatb=[hs,rs], tcatb=[ts,rs] in bf16 ----------------
__global__ void catb_kernel(const float* __restrict__ ent_emb, const float* __restrict__ rs,
                            const int* __restrict__ hts,
                            unsigned short* __restrict__ hcatb, unsigned short* __restrict__ tcatb) {
    int n = blockIdx.x;             // 512
    int b = n >> 8;
    int h_e = hts[n*2+0], t_e = hts[n*2+1];
    const float* eh = ent_emb + (long)(b*E_ + h_e)*D_;
    const float* et = ent_emb + (long)(b*E_ + t_e)*D_;
    const float* r  = rs + (long)n*D_;
    for (int k = threadIdx.x; k < D_; k += 256) {
        hcatb[(long)n*1536 + k] = f2bf(eh[k]);
        tcatb[(long)n*1536 + k] = f2bf(et[k]);
        unsigned short rb = f2bf(r[k]);
        hcatb[(long)n*1536 + 768 + k] = rb;
        tcatb[(long)n*1536 + 768 + k] = rb;
    }
}

// ---------------- Generic MFMA GEMM (double-buffered), 32x32 tiles ----------------
struct MfmaJob {
    const unsigned short* A[4];
    const unsigned short* Bt[4];
    const void* bias[4];
    void* C[4];
    int K[4];
    int ldc[4];
    int act[4];
    int obf[4];
};

__global__ void mfma_nt2_kernel(MfmaJob args, const int* __restrict__ dtf) {
    int z = blockIdx.z;
    const unsigned short* A  = args.A[z];
    const unsigned short* Bt = args.Bt[z];
    const void* bias = args.bias[z];
    void* C = args.C[z];
    int K = args.K[z], ldc = args.ldc[z], act = args.act[z], obf = args.obf[z];
    __shared__ unsigned short Al[2][32][72];
    __shared__ unsigned short Btl[2][32][72];
    int m0 = blockIdx.x*32, n0 = blockIdx.y*32;
    int tid = threadIdx.x, wave = tid>>6, lane = tid&63;
    int lm = lane&15, lq = lane>>4;
    int rowg = wave>>1, cgrp = wave&1;   // wave -> (row half, col half)
    int rr = tid >> 3;                // 0..31
    int kc = (tid & 7) * 8;           // col offset in ushorts
    uint4 ra, rb;

    ra = *(const uint4*)(A  + (long)(m0+rr)*K + kc);
    rb = *(const uint4*)(Bt + (long)(n0+rr)*K + kc);
    *(uint4*)&Al[0][rr][kc]  = ra;
    *(uint4*)&Btl[0][rr][kc] = rb;

    int nst = K >> 6;
    f32x4 acc = {};
    for (int ks = 0; ks < nst; ks++) {
        __syncthreads();
        if (ks+1 < nst) {
            int k0 = (ks+1) << 6;
            ra = *(const uint4*)(A  + (long)(m0+rr)*K + k0 + kc);
            rb = *(const uint4*)(Bt + (long)(n0+rr)*K + k0 + kc);
        }
        int cb = ks & 1;
        #pragma unroll
        for (int half = 0; half < 2; half++) {
            bf16x8 af  = *(bf16x8*)&Al[cb][rowg*16+lm][half*32+lq*8];
            bf16x8 bfr = *(bf16x8*)&Btl[cb][cgrp*16+lm][half*32+lq*8];
            acc = __builtin_amdgcn_mfma_f32_16x16x32_bf16(af, bfr, acc, 0, 0, 0);
        }
        if (ks+1 < nst) {
            int nb = (ks+1) & 1;
            *(uint4*)&Al[nb][rr][kc]  = ra;
            *(uint4*)&Btl[nb][rr][kc] = rb;
        }
    }
    int isbf = dtf[0];
    int n = n0 + cgrp*16 + lm;
    float bia = bias ? ldIn(bias, n, isbf) : 0.f;
    #pragma unroll
    for (int r = 0; r < 4; r++) {
        int m = m0 + rowg*16 + lq*4 + r;
        float v = acc[r] + bia;
        if (act == 1) v = tanhf(v);
        if (obf) ((unsigned short*)C)[(long)m*ldc + n] = f2bf(v);
        else     ((float*)C)[(long)m*ldc + n] = v;
    }
}

// ================= r1 via MFMA =================
// v8: fragment-major WBt + c-split waves. v7's diagnosis: per-lane fragment
// loads were row-strided (16 128-B lines per load instr, half the bytes
// wasted) and both row-group waves loaded the same fragments -> 448
// line-txns per block-step, L1-miss-throughput-bound (~32 MSHR x ~300cy L2).
// Now: WBt stores MFMA fragments contiguously (wave load = 64x16B = 8 lines,
// all useful) and the 4 waves split the C dimension ({2,2,2,1} c-tiles),
// each computing all 32 rows -> 14 loads x 8 lines = 112 line-txns per
// block-step, the coalesced optimum. K-loop stays barrier-free with
// register double-buffering. Grid (48,16) x 256 thr; LDS = hz tile only.
__global__ __launch_bounds__(256, 3)
void r1_mfma_kernel(const float* __restrict__ hz, const float* __restrict__ tz,
                    const unsigned short* __restrict__ WBt,
                    float* __restrict__ partial) {
    __shared__ float hzL[32][17];
    int kz = blockIdx.x;
    int nb0 = blockIdx.y * 32;
    int gk0 = kz * 16;               // global k-step base
    int gi0 = kz * 16;               // hz col base
    int g0 = (kz * KCHUNK_) >> 12;   // tz group, fixed for the whole chunk
    int tid = threadIdx.x;
    int wave = tid >> 6, lane = tid & 63;
    int lm = lane & 15;
    int ctb = wave * 2;              // c-tile base: 0,2,4,6
    int nct = (wave < 3) ? 2 : 1;    // c-tiles this wave computes

    // hz tile 32 rows x 16 cols -> LDS (512 floats, 1 float2 per thread)
    {
        int r = tid >> 3, q = (tid & 7) * 2;
        float2 v = *(const float2*)(hz + (long)(nb0 + r)*EMB_ + gi0 + q);
        hzL[r][q] = v.x; hzL[r][q+1] = v.y;
    }
    // tz fragments for BOTH row-groups (rows rg*16+lm), f32 regs (32 VGPR)
    int lq = lane >> 4;
    f32x8 tza[2], tzb[2];            // [rowg], halves 0/1
    #pragma unroll
    for (int rg = 0; rg < 2; rg++) {
        const float* tp = tz + (long)(nb0 + rg*16 + lm)*EMB_ + g0*64;
        float4 x0 = *(const float4*)(tp + lq*8);
        float4 y0 = *(const float4*)(tp + lq*8 + 4);
        float4 x1 = *(const float4*)(tp + 32 + lq*8);
        float4 y1 = *(const float4*)(tp + 32 + lq*8 + 4);
        tza[rg][0]=x0.x; tza[rg][1]=x0.y; tza[rg][2]=x0.z; tza[rg][3]=x0.w;
        tza[rg][4]=y0.x; tza[rg][5]=y0.y; tza[rg][6]=y0.z; tza[rg][7]=y0.w;
        tzb[rg][0]=x1.x; tzb[rg][1]=x1.y; tzb[rg][2]=x1.z; tzb[rg][3]=x1.w;
        tzb[rg][4]=y1.x; tzb[rg][5]=y1.y; tzb[rg][6]=y1.z; tzb[rg][7]=y1.w;
    }
    __syncthreads();   // hzL ready; ONLY barrier in the kernel

    // fragment-major base: lane's 16B at ((t*7+ct)*2+h)*1024B + lane*16B
    const unsigned short* wb = WBt + (long)gk0*TILE_ + lane*8;

    f32x4 acc[2][2] = {};            // [ct][rowg]
    bf16x8 cb[2][2];                 // [ct][h] current B-frags
    #pragma unroll
    for (int ct = 0; ct < 2; ct++)
        if (ct < nct)
            #pragma unroll
            for (int h = 0; h < 2; h++)
                cb[ct][h] = *(const bf16x8*)(wb + ((ctb+ct)*2 + h)*512);

    #pragma unroll 2
    for (int ks = 0; ks < KCHUNK_/64; ks++) {
        // prefetch next step's B-frags (contiguous 1KB per load)
        bf16x8 nbuf[2][2];
        if (ks+1 < KCHUNK_/64) {
            const unsigned short* wn = wb + (long)(ks+1)*TILE_;
            #pragma unroll
            for (int ct = 0; ct < 2; ct++)
                if (ct < nct)
                    #pragma unroll
                    for (int h = 0; h < 2; h++)
                        nbuf[ct][h] = *(const bf16x8*)(wn + ((ctb+ct)*2 + h)*512);
        }
        float hv0 = hzL[lm][ks];
        float hv1 = hzL[16 + lm][ks];
        unsigned short o00[8], o01[8], o10[8], o11[8];  // [rowg][half]
        #pragma unroll
        for (int e = 0; e < 8; e++) {
            o00[e] = f2bf(tza[0][e] * hv0);
            o01[e] = f2bf(tzb[0][e] * hv0);
            o10[e] = f2bf(tza[1][e] * hv1);
            o11[e] = f2bf(tzb[1][e] * hv1);
        }
        bf16x8 a00 = *(bf16x8*)o00, a01 = *(bf16x8*)o01;
        bf16x8 a10 = *(bf16x8*)o10, a11 = *(bf16x8*)o11;
        #pragma unroll
        for (int ct = 0; ct < 2; ct++) {
            if (ct < nct) {
                acc[ct][0] = __builtin_amdgcn_mfma_f32_16x16x32_bf16(a00, cb[ct][0], acc[ct][0], 0, 0, 0);
                acc[ct][0] = __builtin_amdgcn_mfma_f32_16x16x32_bf16(a01, cb[ct][1], acc[ct][0], 0, 0, 0);
                acc[ct][1] = __builtin_amdgcn_mfma_f32_16x16x32_bf16(a10, cb[ct][0], acc[ct][1], 0, 0, 0);
                acc[ct][1] = __builtin_amdgcn_mfma_f32_16x16x32_bf16(a11, cb[ct][1], acc[ct][1], 0, 0, 0);
            }
        }
        if (ks+1 < KCHUNK_/64) {
            #pragma unroll
            for (int ct = 0; ct < 2; ct++)
                if (ct < nct)
                    #pragma unroll
                    for (int h = 0; h < 2; h++)
                        cb[ct][h] = nbuf[ct][h];
        }
    }
    // epilogue: wave w writes c-tiles ctb..; wave 3 also zeros c-tile 7
    // (c 112..127) so every 512-B partial chunk is fully written (no RMW).
    #pragma unroll
    for (int ct = 0; ct < 2; ct++) {
        if (ct < nct || wave == 3) {
            int c = (ctb + ct)*16 + lm;
            #pragma unroll
            for (int rg = 0; rg < 2; rg++) {
                #pragma unroll
                for (int r = 0; r < 4; r++) {
                    int nl = rg*16 + lq*4 + r;
                    float v = (ct < nct) ? acc[ct][rg][r] : 0.f;
                    partial[((long)(nb0+nl)*KSPLIT_ + kz)*PSTR_ + c] = v;
                }
            }
        }
    }
}

// ---------------- fused: r1 streaming reduce + r2/r3 LSE + final projection ----------------
__global__ void r23out_kernel(const float* __restrict__ partial, const void* __restrict__ b_rel,
                              const float* __restrict__ mu, const float* __restrict__ c23,
                              const int* __restrict__ hts, const int* __restrict__ mention_idx,
                              const float* __restrict__ W_bilF, const void* __restrict__ b_bil,
                              void* __restrict__ out, const int* __restrict__ dtf) {
    int bp = blockIdx.x;
    int b = bp >> 8;
    int c = threadIdx.x;
    int isbf = dtf[0];
    __shared__ float row[292];
    if (c < C_) {
        const float* pr = partial + (long)bp*KSPLIT_*PSTR_;
        float r1v = 0.f;
        #pragma unroll 8
        for (int kz = 0; kz < KSPLIT_; kz++)
            r1v += pr[kz*PSTR_ + c];
        r1v += ldIn(b_rel, c, isbf);
        int h_e = hts[bp*2+0], t_e = hts[bp*2+1];
        const float* mu2h = mu;
        const float* mu2t = mu + 32768;
        const float* mu3h = mu + 65536;
        const float* mu3t = mu + 98304;
        float ah2[4], at2[4], ah3[4], at3[4];
        for (int m = 0; m < 4; m++) {
            int emh = mention_idx[(b*E_ + h_e)*M_ + m];
            int emt = mention_idx[(b*E_ + t_e)*M_ + m];
            ah2[m] = mu2h[(long)(b*128 + emh)*128 + c];
            ah3[m] = mu3h[(long)(b*128 + emh)*128 + c];
            at2[m] = mu2t[(long)(b*128 + emt)*128 + c];
            at3[m] = mu3t[(long)(b*128 + emt)*128 + c];
        }
        float c2 = c23[c], c3 = c23[C_ + c];
        float v2[16], v3[16];
        int q = 0;
        for (int i = 0; i < 4; i++) {
            for (int j = 0; j < 4; j++, q++) {
                float x2 = ah2[i] + at2[j] + c2;
                v2[q] = tanhf(x2);
                float x3 = ah3[i] + at3[j] + c3;
                float t = tanhf(0.7978845608028654f * (x3 + 0.044715f*x3*x3*x3));
                v3[q] = 0.5f * x3 * (1.0f + t);
            }
        }
        float m2 = v2[0], m3 = v3[0];
        for (q = 1; q < 16; q++) { m2 = fmaxf(m2, v2[q]); m3 = fmaxf(m3, v3[q]); }
        float s2 = 0.f, s3 = 0.f;
        for (q = 0; q < 16; q++) { s2 += expf(v2[q]-m2); s3 += expf(v3[q]-m3); }
        row[c]        = r1v;
        row[C_ + c]   = m2 + logf(s2);
        row[2*C_ + c] = m3 + logf(s3);
    }
    __syncthreads();
    if (c >= C_) return;
    float a0 = 0.f, a1 = 0.f, a2 = 0.f, a3 = 0.f;
    #pragma unroll 4
    for (int k = 0; k < 288; k += 4) {
        a0 += row[k+0] * W_bilF[(k+0)*C_ + c];
        a1 += row[k+1] * W_bilF[(k+1)*C_ + c];
        a2 += row[k+2] * W_bilF[(k+2)*C_ + c];
        a3 += row[k+3] * W_bilF[(k+3)*C_ + c];
    }
    a0 += row[288] * W_bilF[288*C_ + c];
    a1 += row[289] * W_bilF[289*C_ + c];
    a2 += row[290] * W_bilF[290*C_ + c];
    float v = a0 + a1 + a2 + a3 + ldIn(b_bil, c, isbf);
    if (isbf) ((bf16*)out)[(long)bp*C_ + c] = (bf16)v;
    else      ((float*)out)[(long)bp*C_ + c] = v;
}

extern "C" void kernel_launch(void* const* d_in, const int* in_sizes, int n_in,
                              void* d_out, int out_size, void* d_ws, size_t ws_size,
                              hipStream_t stream) {
    const void* seq        = d_in[0];
    const void* attn       = d_in[1];
    const int*  entity_pos = (const int*)d_in[2];
    const int*  hts        = (const int*)d_in[3];
    const int*  mention_idx= (const int*)d_in[4];
    const void* W_head     = d_in[5];
    const void* b_head     = d_in[6];
    const void* W_tail     = d_in[7];
    const void* b_tail     = d_in[8];
    const void* W_rel      = d_in[9];
    const void* b_rel      = d_in[10];
    const void* W_fh       = d_in[11];
    const void* W_ft       = d_in[12];
    const void* b_f        = d_in[13];
    const void* W_unet     = d_in[14];
    const void* b_unet     = d_in[15];
    const void* W_mlp      = d_in[16];
    const void* b_mlp      = d_in[17];
    const void* W_bil      = d_in[18];
    const void* b_bil      = d_in[19];

    float* w = (float*)d_ws;
    int*   dtf      = (int*)w;                               // 64
    unsigned short* mentb = (unsigned short*)(w + 64);       // 98304 fl
    float* ent_emb  = w + 98368;                             // 49152
    float* ent_att  = w + 147520;                            // 393216
    unsigned short* htb = (unsigned short*)(w + 540736);     // 131072 fl
    float* rs       = w + 671808;                            // 393216
    float* hz       = w + 1065024;                           // 393216
    float* tz       = w + 1458240;                           // 393216
    float* mu       = w + 1851456;                           // 131072
    float* c23      = w + 1982528;                           // 256
    unsigned short* seqT  = (unsigned short*)(w + 1982784);  // 393216 fl
    unsigned short* WhT   = (unsigned short*)(w + 2376000);  // 589824 fl
    unsigned short* WtT   = (unsigned short*)(w + 2965824);  // 589824 fl
    unsigned short* WfhT  = (unsigned short*)(w + 3555648);  // 294912 fl
    unsigned short* WftT  = (unsigned short*)(w + 3850560);  // 294912 fl
    unsigned short* WunetT= (unsigned short*)(w + 4145472);  // 49152 fl
    unsigned short* WmlpT = (unsigned short*)(w + 4194624);  // 49152 fl
    unsigned short* Tbh   = (unsigned short*)(w + 4243776);  // 98304 fl
    unsigned short* Tbt   = (unsigned short*)(w + 4342080);  // 98304 fl
    unsigned short* hcatb = (unsigned short*)(w + 4440384);  // 393216 fl
    unsigned short* tcatb = (unsigned short*)(w + 4833600);  // 393216 fl
    unsigned short* WBt   = (unsigned short*)(w + 5226816);  // 2752512 fl (fragment-major tiles)
    float* partial  = w + 7979328;                           // 3670016 fl (used: 512*48*128 = 3145728)
    float* W_bilF   = w + 11649344;                          // 28227 fl

    // 0. dtype detection + c23 init
    dtype_detect<<<1, 256, 0, stream>>>(seq, dtf, c23);
    // 1. prep: c23 (z=0) + W_rel conv (z=1, fragment-major) + transposes + W_bilF
    {
        PrepArgs a = {};
        const void* srcs[8] = {W_head, W_tail, W_fh, W_ft, W_unet, W_mlp, seq, seq};
        long offs[8]   = {0,0,0,0,0,0,0,393216};
        int Ks[8]      = {1536,1536,768,768,768,768,512,512};
        int Ncols8[8]  = {768,768,768,768,97,97,768,768};
        int Npads[8]   = {768,768,768,768,128,128,768,768};
        unsigned short* dsts[8] = {WhT, WtT, WfhT, WftT, WunetT, WmlpT, seqT, seqT+393216};
        for (int z = 0; z < 8; z++) {
            a.src[z]=srcs[z]; a.off[z]=offs[z]; a.K[z]=Ks[z];
            a.Ncols[z]=Ncols8[z]; a.Npad[z]=Npads[z]; a.dst[z]=dsts[z];
        }
        a.W_bil = W_bil; a.W_bilF = W_bilF;
        a.b_f = b_f; a.W_unet = W_unet; a.b_unet = b_unet;
        a.W_mlp = W_mlp; a.b_mlp = b_mlp; a.c23 = c23;
        a.W_rel = W_rel; a.WBt = WBt;
        prep_kernel<<<dim3(48, 16, 11), 256, 0, stream>>>(a, dtf);
    }
    // 2. gather: entatt + ment
    gather_kernel<<<768 + 64, 256, 0, stream>>>(seq, attn, entity_pos, mentb, ent_emb, ent_att, dtf);
    // 3. ht attention (normalized, bf16)
    htatt_kernel<<<N_, 256, 0, stream>>>(ent_att, hts, htb);
    // 4. gemmA: rs (z=0,1) + T_{h,t} (z=2,3)  [32x32 tiles]
    {
        MfmaJob ga = {};
        for (int z = 0; z < 2; z++) {
            ga.A[z] = htb + (long)z*256*512; ga.Bt[z] = seqT + (long)z*393216;
            ga.bias[z] = nullptr; ga.C[z] = rs + (long)z*256*768;
            ga.K[z] = 512; ga.ldc[z] = 768; ga.act[z] = 0; ga.obf[z] = 0;
        }
        ga.A[2] = mentb; ga.Bt[2] = WfhT; ga.bias[2] = nullptr; ga.C[2] = Tbh;
        ga.K[2] = 768; ga.ldc[2] = 768; ga.act[2] = 0; ga.obf[2] = 1;
        ga.A[3] = mentb; ga.Bt[3] = WftT; ga.bias[3] = nullptr; ga.C[3] = Tbt;
        ga.K[3] = 768; ga.ldc[3] = 768; ga.act[3] = 0; ga.obf[3] = 1;
        mfma_nt2_kernel<<<dim3(8, 24, 4), 256, 0, stream>>>(ga, dtf);
    }
    // 5. concatenated inputs (bf16)
    catb_kernel<<<N_, 256, 0, stream>>>(ent_emb, rs, hts, hcatb, tcatb);
    // 6. gemmB: hz/tz = tanh(cat @ W + b)
    {
        MfmaJob ga = {};
        ga.A[0] = hcatb; ga.Bt[0] = WhT; ga.bias[0] = b_head; ga.C[0] = hz;
        ga.A[1] = tcatb; ga.Bt[1] = WtT; ga.bias[1] = b_tail; ga.C[1] = tz;
        for (int z = 0; z < 2; z++) { ga.K[z] = 1536; ga.ldc[z] = 768; ga.act[z] = 1; ga.obf[z] = 0; }
        mfma_nt2_kernel<<<dim3(16, 24, 2), 256, 0, stream>>>(ga, dtf);
    }
    // 7. gemmC: mu_q = T @ W_{unet,mlp}
    {
        MfmaJob ga = {};
        const unsigned short* As[4] = {Tbh, Tbt, Tbh, Tbt};
        const unsigned short* Bs[4] = {WunetT, WunetT, WmlpT, WmlpT};
        for (int q = 0; q < 4; q++) {
            ga.A[q] = As[q]; ga.Bt[q] = Bs[q]; ga.bias[q] = nullptr;
            ga.C[q] = mu + q*32768;
            ga.K[q] = 768; ga.ldc[q] = 128; ga.act[q] = 0; ga.obf[q] = 0;
        }
        mfma_nt2_kernel<<<dim3(8, 4, 4), 256, 0, stream>>>(ga, dtf);
    }
    // 8. r1 partials via MFMA (fragment-major loads, c-split waves, no K-loop barrier)
    r1_mfma_kernel<<<dim3(KSPLIT_, 16), 256, 0, stream>>>(hz, tz, WBt, partial);
    // 9. fused reduce + r2/r3 + final projection
    r23out_kernel<<<N_, 128, 0, stream>>>(partial, b_rel, mu, c23, hts, mention_idx,
                                          W_bilF, b_bil, d_out, dtf);
}

// Round 10
// 215.680 us; speedup vs baseline: 1.1315x; 1.0106x over previous
//
#include <hip/hip_runtime.h>
#include <hip/hip_bf16.h>

// Problem constants
#define B_  2
#define L_  512
#define D_  768
#define H_  12
#define E_  32
#define M_  4
#define P_  256
#define EMB_ 768
#define BS_ 64
#define C_  97
#define N_  (B_*P_)   // 512

#define KTOT_    49152      // EMB*BS
#define CPAD_    112        // 97 padded to 7*16
#define KSPLIT_  48
#define KCHUNK_  (KTOT_/KSPLIT_)   // 1024, 16 ks-steps of 64
#define PSTR_    128        // partial chunk stride (floats): 512 B, cache-line exclusive
#define TILE_    (CPAD_*64) // 7168 ushorts = 14336 B per k-step tile of WBt (fragment-major)

typedef __hip_bfloat16 bf16;
typedef __attribute__((ext_vector_type(8))) short bf16x8;
typedef __attribute__((ext_vector_type(4))) float f32x4;
typedef __attribute__((ext_vector_type(8))) float f32x8;

__device__ inline float ldIn(const void* p, long idx, int isbf) {
    return isbf ? (float)((const bf16*)p)[idx] : ((const float*)p)[idx];
}

__device__ inline unsigned short f2bf(float f) {
    bf16 h = (bf16)f;
    return *(unsigned short*)&h;
}

// Per-wave inline dtype detection (replaces the serial dtype_detect kernel).
// Samples 64 ushorts of seq: bf16 N(0,1) data never has (u>>7)&0xFF >= 140
// (exp<=~129); fp32 data's low-halves are uniform random -> ~45% hit rate,
// P(false bf16) = 0.55^32 ~ 5e-9. Must be called with the full wave active.
__device__ inline int detect_bf(const void* seqd) {
    const unsigned short* u = (const unsigned short*)seqd;
    int lane = threadIdx.x & 63;
    unsigned short e = (u[lane] >> 7) & 0xFF;
    unsigned long long m = __ballot(e >= 140);
    return m == 0ull;
}

// ---------------- prep: z=0 c23 partials (16 blocks, non-atomic), z=1 W_rel
// fragment-major conv, z=2..9 transposes, z=10 W_bil->f32. No dtf dependency.
struct PrepArgs {
    const void* src[8];
    long off[8];
    int K[8];
    int Ncols[8];
    int Npad[8];
    unsigned short* dst[8];
    const void* W_bil;  float* W_bilF;
    const void* b_f; const void* W_unet; const void* b_unet;
    const void* W_mlp; const void* b_mlp; float* c23p;
    const void* W_rel; unsigned short* WBt;
    const void* seqd;
};

union PrepSm {
    float T[32][65];                 // 8320 B
    unsigned short TW[CPAD_][72];    // 16128 B
};

__global__ void prep_kernel(PrepArgs a) {
    int isbf = detect_bf(a.seqd);
    int z = blockIdx.z;
    __shared__ PrepSm sm;
    int tid = threadIdx.x;
    if (z == 0) {
        // c23 partials: 16 blocks x 48 d-rows -> c23p[lin][2][97], summed in r23out
        int lin = blockIdx.y*48 + blockIdx.x;
        if (lin >= 16) return;
        int c = tid;
        if (c >= C_) return;
        float s2 = 0.f, s3 = 0.f;
        int d0 = lin*48;
        for (int i = 0; i < 48; i++) {
            int d = d0 + i;
            float bf = ldIn(a.b_f, d, isbf);
            s2 += bf * ldIn(a.W_unet, (long)d*C_ + c, isbf);
            s3 += bf * ldIn(a.W_mlp,  (long)d*C_ + c, isbf);
        }
        if (lin == 0) {
            s2 += ldIn(a.b_unet, c, isbf);
            s3 += ldIn(a.b_mlp,  c, isbf);
        }
        a.c23p[lin*194 + c]      = s2;
        a.c23p[lin*194 + 97 + c] = s3;
    } else if (z == 1) {
        // W_rel -> WBt FRAGMENT-MAJOR: per k-step tile t, item idx=(ct*2+h)*64+l
        // stores the 8 bf16 lane l of c-tile ct, k-half h consumes as MFMA B.
        int lin = blockIdx.y*48 + blockIdx.x;
        if (lin >= KTOT_/64) return;
        int k0 = lin * 64;
        for (int idx = tid; idx < 64*97; idx += 256) {
            int kk = idx / 97, c = idx % 97;
            sm.TW[c][kk] = f2bf(ldIn(a.W_rel, (long)(k0+kk)*C_ + c, isbf));
        }
        for (int idx = tid; idx < 15*64; idx += 256) {
            sm.TW[97 + (idx>>6)][idx & 63] = 0;
        }
        __syncthreads();
        unsigned short* tb = a.WBt + (long)lin*TILE_;
        for (int t = 0; t < 4; t++) {
            int idx = tid + t*256;      // < 896
            if (idx < 896) {
                int l  = idx & 63;
                int h  = (idx >> 6) & 1;
                int ct = idx >> 7;
                int row = ct*16 + (l & 15);
                int col = h*32 + (l >> 4)*8;
                *(uint4*)(tb + idx*8) = *(uint4*)&sm.TW[row][col];
            }
        }
    } else if (z <= 9) {
        int j = z - 2;
        int K = a.K[j], Ncols = a.Ncols[j], Npad = a.Npad[j];
        int k0 = blockIdx.x*32, n0 = blockIdx.y*64;
        if (k0 >= K || n0 >= Npad) return;
        const void* src = a.src[j];
        long off = a.off[j];
        unsigned short* dst = a.dst[j];
        int c64 = tid & 63, r4 = tid >> 6;
        for (int p = 0; p < 8; p++) {
            int r = r4 + p*4;
            int n = n0 + c64;
            sm.T[r][c64] = (n < Ncols) ? ldIn(src, off + (long)(k0+r)*Ncols + n, isbf) : 0.f;
        }
        __syncthreads();
        int cc = tid & 31, n8 = tid >> 5;
        for (int p = 0; p < 8; p++) {
            int nn = n8 + p*8;
            dst[(long)(n0+nn)*K + k0 + cc] = f2bf(sm.T[cc][nn]);
        }
    } else {
        int lin = blockIdx.y*48 + blockIdx.x;
        int idx = lin*256 + tid;
        if (idx < 291*C_) a.W_bilF[idx] = ldIn(a.W_bil, idx, isbf);
    }
}

// ---------------- ghatt: merged gather + htatt ----------------
// Blocks 0..511: ht_att computed DIRECTLY from attn (no ent_att intermediate;
// the mention-means' 0.25*0.25 is folded into the h-product). Blocks 512..575:
// mention gather (mentb bf16 + ent_emb logsumexp), unchanged math.
__global__ void ghatt_kernel(const void* __restrict__ seq, const void* __restrict__ attn,
                             const int* __restrict__ entity_pos, const int* __restrict__ hts,
                             unsigned short* __restrict__ mentb, float* __restrict__ ent_emb,
                             unsigned short* __restrict__ htb) {
    int isbf = detect_bf(seq);
    if (blockIdx.x < 512) {
        int bp = blockIdx.x;
        int b = bp >> 8;
        int h_e = hts[bp*2+0], t_e = hts[bp*2+1];
        int ph[M_], pt[M_];
        for (int m = 0; m < M_; m++) {
            ph[m] = entity_pos[(b*E_ + h_e)*M_ + m] + 1;
            pt[m] = entity_pos[(b*E_ + t_e)*M_ + m] + 1;
        }
        __shared__ float red[256];
        float v[2];
        for (int t = 0; t < 2; t++) {
            int l = threadIdx.x + t*256;
            float s = 0.f;
            for (int h = 0; h < H_; h++) {
                long hb = ((long)(b*H_ + h))*L_;
                float ha = 0.f, ta = 0.f;
                for (int m = 0; m < M_; m++) {
                    ha += ldIn(attn, (hb + ph[m])*L_ + l, isbf);
                    ta += ldIn(attn, (hb + pt[m])*L_ + l, isbf);
                }
                s += ha * ta;
            }
            v[t] = s * (0.0625f / H_);   // 0.25^2 mention means / H
        }
        red[threadIdx.x] = v[0] + v[1];
        __syncthreads();
        for (int off = 128; off > 0; off >>= 1) {
            if (threadIdx.x < off) red[threadIdx.x] += red[threadIdx.x+off];
            __syncthreads();
        }
        float inv = 1.0f / (red[0] + 1e-5f);
        for (int t = 0; t < 2; t++) {
            int l = threadIdx.x + t*256;
            htb[(long)bp*L_ + l] = f2bf(v[t] * inv);
        }
    } else {
        int be = blockIdx.x - 512;     // 0..63
        int b = be >> 5;
        int pos[M_];
        for (int m = 0; m < M_; m++) pos[m] = entity_pos[be*M_+m] + 1;
        for (int d = threadIdx.x; d < D_; d += 256) {
            float x[M_];
            for (int m = 0; m < M_; m++) {
                x[m] = ldIn(seq, ((long)b*L_ + pos[m])*D_ + d, isbf);
                mentb[((long)be*M_ + m)*D_ + d] = f2bf(x[m]);
            }
            float mx = fmaxf(fmaxf(x[0],x[1]), fmaxf(x[2],x[3]));
            float s = expf(x[0]-mx)+expf(x[1]-mx)+expf(x[2]-mx)+expf(x[3]-mx);
            ent_emb[(long)be*D_ + d] = mx + logf(s);
        }
    }
}

// ---------------- catb: hcatb=[hs,rs], tcatb=[ts,rs] in bf16 ----------------
__global__ void catb_kernel(const float* __restrict__ ent_emb, const float* __restrict__ rs,
                            const int* __restrict__ hts,
                            unsigned short* __restrict__ hcatb, unsigned short* __restrict__ tcatb) {
    int n = blockIdx.x;             // 512
    int b = n >> 8;
    int h_e = hts[n*2+0], t_e = hts[n*2+1];
    const float* eh = ent_emb + (long)(b*E_ + h_e)*D_;
    const float* et = ent_emb + (long)(b*E_ + t_e)*D_;
    const float* r  = rs + (long)n*D_;
    for (int k = threadIdx.x; k < D_; k += 256) {
        hcatb[(long)n*1536 + k] = f2bf(eh[k]);
        tcatb[(long)n*1536 + k] = f2bf(et[k]);
        unsigned short rb = f2bf(r[k]);
        hcatb[(long)n*1536 + 768 + k] = rb;
        tcatb[(long)n*1536 + 768 + k] = rb;
    }
}

// ---------------- Generic MFMA GEMM (double-buffered), 32x32 tiles ----------------
// Now supports up to 8 z-jobs with per-job M/N bounds (early exit) so small
// jobs (gemmC's mu) can ride in the same launch as big ones (gemmB).
struct MfmaJob {
    const unsigned short* A[8];
    const unsigned short* Bt[8];
    const void* bias[8];
    void* C[8];
    const void* seqd;
    int K[8];
    int ldc[8];
    int act[8];
    int obf[8];
    int Mt[8];
    int Nt[8];
};

__global__ void mfma_nt2_kernel(MfmaJob args) {
    int z = blockIdx.z;
    int m0 = blockIdx.x*32, n0 = blockIdx.y*32;
    if (m0 >= args.Mt[z] || n0 >= args.Nt[z]) return;
    int isbf = detect_bf(args.seqd);
    const unsigned short* A  = args.A[z];
    const unsigned short* Bt = args.Bt[z];
    const void* bias = args.bias[z];
    void* C = args.C[z];
    int K = args.K[z], ldc = args.ldc[z], act = args.act[z], obf = args.obf[z];
    __shared__ unsigned short Al[2][32][72];
    __shared__ unsigned short Btl[2][32][72];
    int tid = threadIdx.x, wave = tid>>6, lane = tid&63;
    int lm = lane&15, lq = lane>>4;
    int rowg = wave>>1, cgrp = wave&1;   // wave -> (row half, col half)
    int rr = tid >> 3;                // 0..31
    int kc = (tid & 7) * 8;           // col offset in ushorts
    uint4 ra, rb;

    ra = *(const uint4*)(A  + (long)(m0+rr)*K + kc);
    rb = *(const uint4*)(Bt + (long)(n0+rr)*K + kc);
    *(uint4*)&Al[0][rr][kc]  = ra;
    *(uint4*)&Btl[0][rr][kc] = rb;

    int nst = K >> 6;
    f32x4 acc = {};
    for (int ks = 0; ks < nst; ks++) {
        __syncthreads();
        if (ks+1 < nst) {
            int k0 = (ks+1) << 6;
            ra = *(const uint4*)(A  + (long)(m0+rr)*K + k0 + kc);
            rb = *(const uint4*)(Bt + (long)(n0+rr)*K + k0 + kc);
        }
        int cb = ks & 1;
        #pragma unroll
        for (int half = 0; half < 2; half++) {
            bf16x8 af  = *(bf16x8*)&Al[cb][rowg*16+lm][half*32+lq*8];
            bf16x8 bfr = *(bf16x8*)&Btl[cb][cgrp*16+lm][half*32+lq*8];
            acc = __builtin_amdgcn_mfma_f32_16x16x32_bf16(af, bfr, acc, 0, 0, 0);
        }
        if (ks+1 < nst) {
            int nb = (ks+1) & 1;
            *(uint4*)&Al[nb][rr][kc]  = ra;
            *(uint4*)&Btl[nb][rr][kc] = rb;
        }
    }
    int n = n0 + cgrp*16 + lm;
    float bia = bias ? ldIn(bias, n, isbf) : 0.f;
    #pragma unroll
    for (int r = 0; r < 4; r++) {
        int m = m0 + rowg*16 + lq*4 + r;
        float v = acc[r] + bia;
        if (act == 1) v = tanhf(v);
        if (obf) ((unsigned short*)C)[(long)m*ldc + n] = f2bf(v);
        else     ((float*)C)[(long)m*ldc + n] = v;
    }
}

// ================= r1 via MFMA (v8, unchanged) =================
// Fragment-major WBt + c-split waves; barrier-free K-loop with register
// double-buffering. 112 coalesced line-txns per block-step.
__global__ __launch_bounds__(256, 3)
void r1_mfma_kernel(const float* __restrict__ hz, const float* __restrict__ tz,
                    const unsigned short* __restrict__ WBt,
                    float* __restrict__ partial) {
    __shared__ float hzL[32][17];
    int kz = blockIdx.x;
    int nb0 = blockIdx.y * 32;
    int gk0 = kz * 16;               // global k-step base
    int gi0 = kz * 16;               // hz col base
    int g0 = (kz * KCHUNK_) >> 12;   // tz group, fixed for the whole chunk
    int tid = threadIdx.x;
    int wave = tid >> 6, lane = tid & 63;
    int lm = lane & 15;
    int ctb = wave * 2;              // c-tile base: 0,2,4,6
    int nct = (wave < 3) ? 2 : 1;    // c-tiles this wave computes

    {
        int r = tid >> 3, q = (tid & 7) * 2;
        float2 v = *(const float2*)(hz + (long)(nb0 + r)*EMB_ + gi0 + q);
        hzL[r][q] = v.x; hzL[r][q+1] = v.y;
    }
    int lq = lane >> 4;
    f32x8 tza[2], tzb[2];            // [rowg], halves 0/1
    #pragma unroll
    for (int rg = 0; rg < 2; rg++) {
        const float* tp = tz + (long)(nb0 + rg*16 + lm)*EMB_ + g0*64;
        float4 x0 = *(const float4*)(tp + lq*8);
        float4 y0 = *(const float4*)(tp + lq*8 + 4);
        float4 x1 = *(const float4*)(tp + 32 + lq*8);
        float4 y1 = *(const float4*)(tp + 32 + lq*8 + 4);
        tza[rg][0]=x0.x; tza[rg][1]=x0.y; tza[rg][2]=x0.z; tza[rg][3]=x0.w;
        tza[rg][4]=y0.x; tza[rg][5]=y0.y; tza[rg][6]=y0.z; tza[rg][7]=y0.w;
        tzb[rg][0]=x1.x; tzb[rg][1]=x1.y; tzb[rg][2]=x1.z; tzb[rg][3]=x1.w;
        tzb[rg][4]=y1.x; tzb[rg][5]=y1.y; tzb[rg][6]=y1.z; tzb[rg][7]=y1.w;
    }
    __syncthreads();   // hzL ready; ONLY barrier in the kernel

    const unsigned short* wb = WBt + (long)gk0*TILE_ + lane*8;

    f32x4 acc[2][2] = {};            // [ct][rowg]
    bf16x8 cb[2][2];                 // [ct][h] current B-frags
    #pragma unroll
    for (int ct = 0; ct < 2; ct++)
        if (ct < nct)
            #pragma unroll
            for (int h = 0; h < 2; h++)
                cb[ct][h] = *(const bf16x8*)(wb + ((ctb+ct)*2 + h)*512);

    #pragma unroll 2
    for (int ks = 0; ks < KCHUNK_/64; ks++) {
        bf16x8 nbuf[2][2];
        if (ks+1 < KCHUNK_/64) {
            const unsigned short* wn = wb + (long)(ks+1)*TILE_;
            #pragma unroll
            for (int ct = 0; ct < 2; ct++)
                if (ct < nct)
                    #pragma unroll
                    for (int h = 0; h < 2; h++)
                        nbuf[ct][h] = *(const bf16x8*)(wn + ((ctb+ct)*2 + h)*512);
        }
        float hv0 = hzL[lm][ks];
        float hv1 = hzL[16 + lm][ks];
        unsigned short o00[8], o01[8], o10[8], o11[8];
        #pragma unroll
        for (int e = 0; e < 8; e++) {
            o00[e] = f2bf(tza[0][e] * hv0);
            o01[e] = f2bf(tzb[0][e] * hv0);
            o10[e] = f2bf(tza[1][e] * hv1);
            o11[e] = f2bf(tzb[1][e] * hv1);
        }
        bf16x8 a00 = *(bf16x8*)o00, a01 = *(bf16x8*)o01;
        bf16x8 a10 = *(bf16x8*)o10, a11 = *(bf16x8*)o11;
        #pragma unroll
        for (int ct = 0; ct < 2; ct++) {
            if (ct < nct) {
                acc[ct][0] = __builtin_amdgcn_mfma_f32_16x16x32_bf16(a00, cb[ct][0], acc[ct][0], 0, 0, 0);
                acc[ct][0] = __builtin_amdgcn_mfma_f32_16x16x32_bf16(a01, cb[ct][1], acc[ct][0], 0, 0, 0);
                acc[ct][1] = __builtin_amdgcn_mfma_f32_16x16x32_bf16(a10, cb[ct][0], acc[ct][1], 0, 0, 0);
                acc[ct][1] = __builtin_amdgcn_mfma_f32_16x16x32_bf16(a11, cb[ct][1], acc[ct][1], 0, 0, 0);
            }
        }
        if (ks+1 < KCHUNK_/64) {
            #pragma unroll
            for (int ct = 0; ct < 2; ct++)
                if (ct < nct)
                    #pragma unroll
                    for (int h = 0; h < 2; h++)
                        cb[ct][h] = nbuf[ct][h];
        }
    }
    #pragma unroll
    for (int ct = 0; ct < 2; ct++) {
        if (ct < nct || wave == 3) {
            int c = (ctb + ct)*16 + lm;
            #pragma unroll
            for (int rg = 0; rg < 2; rg++) {
                #pragma unroll
                for (int r = 0; r < 4; r++) {
                    int nl = rg*16 + lq*4 + r;
                    float v = (ct < nct) ? acc[ct][rg][r] : 0.f;
                    partial[((long)(nb0+nl)*KSPLIT_ + kz)*PSTR_ + c] = v;
                }
            }
        }
    }
}

// ---------------- fused: r1 streaming reduce + r2/r3 LSE + final projection ----------------
__global__ void r23out_kernel(const float* __restrict__ partial, const void* __restrict__ b_rel,
                              const float* __restrict__ mu, const float* __restrict__ c23p,
                              const int* __restrict__ hts, const int* __restrict__ mention_idx,
                              const float* __restrict__ W_bilF, const void* __restrict__ b_bil,
                              void* __restrict__ out, const void* __restrict__ seqd) {
    int bp = blockIdx.x;
    int b = bp >> 8;
    int c = threadIdx.x;
    int isbf = detect_bf(seqd);
    __shared__ float row[292];
    if (c < C_) {
        const float* pr = partial + (long)bp*KSPLIT_*PSTR_;
        float r1v = 0.f;
        #pragma unroll 8
        for (int kz = 0; kz < KSPLIT_; kz++)
            r1v += pr[kz*PSTR_ + c];
        r1v += ldIn(b_rel, c, isbf);
        int h_e = hts[bp*2+0], t_e = hts[bp*2+1];
        const float* mu2h = mu;
        const float* mu2t = mu + 32768;
        const float* mu3h = mu + 65536;
        const float* mu3t = mu + 98304;
        float ah2[4], at2[4], ah3[4], at3[4];
        for (int m = 0; m < 4; m++) {
            int emh = mention_idx[(b*E_ + h_e)*M_ + m];
            int emt = mention_idx[(b*E_ + t_e)*M_ + m];
            ah2[m] = mu2h[(long)(b*128 + emh)*128 + c];
            ah3[m] = mu3h[(long)(b*128 + emh)*128 + c];
            at2[m] = mu2t[(long)(b*128 + emt)*128 + c];
            at3[m] = mu3t[(long)(b*128 + emt)*128 + c];
        }
        float c2 = 0.f, c3 = 0.f;
        #pragma unroll
        for (int j = 0; j < 16; j++) {
            c2 += c23p[j*194 + c];
            c3 += c23p[j*194 + 97 + c];
        }
        float v2[16], v3[16];
        int q = 0;
        for (int i = 0; i < 4; i++) {
            for (int j = 0; j < 4; j++, q++) {
                float x2 = ah2[i] + at2[j] + c2;
                v2[q] = tanhf(x2);
                float x3 = ah3[i] + at3[j] + c3;
                float t = tanhf(0.7978845608028654f * (x3 + 0.044715f*x3*x3*x3));
                v3[q] = 0.5f * x3 * (1.0f + t);
            }
        }
        float m2 = v2[0], m3 = v3[0];
        for (q = 1; q < 16; q++) { m2 = fmaxf(m2, v2[q]); m3 = fmaxf(m3, v3[q]); }
        float s2 = 0.f, s3 = 0.f;
        for (q = 0; q < 16; q++) { s2 += expf(v2[q]-m2); s3 += expf(v3[q]-m3); }
        row[c]        = r1v;
        row[C_ + c]   = m2 + logf(s2);
        row[2*C_ + c] = m3 + logf(s3);
    }
    __syncthreads();
    if (c >= C_) return;
    float a0 = 0.f, a1 = 0.f, a2 = 0.f, a3 = 0.f;
    #pragma unroll 4
    for (int k = 0; k < 288; k += 4) {
        a0 += row[k+0] * W_bilF[(k+0)*C_ + c];
        a1 += row[k+1] * W_bilF[(k+1)*C_ + c];
        a2 += row[k+2] * W_bilF[(k+2)*C_ + c];
        a3 += row[k+3] * W_bilF[(k+3)*C_ + c];
    }
    a0 += row[288] * W_bilF[288*C_ + c];
    a1 += row[289] * W_bilF[289*C_ + c];
    a2 += row[290] * W_bilF[290*C_ + c];
    float v = a0 + a1 + a2 + a3 + ldIn(b_bil, c, isbf);
    if (isbf) ((bf16*)out)[(long)bp*C_ + c] = (bf16)v;
    else      ((float*)out)[(long)bp*C_ + c] = v;
}

extern "C" void kernel_launch(void* const* d_in, const int* in_sizes, int n_in,
                              void* d_out, int out_size, void* d_ws, size_t ws_size,
                              hipStream_t stream) {
    const void* seq        = d_in[0];
    const void* attn       = d_in[1];
    const int*  entity_pos = (const int*)d_in[2];
    const int*  hts        = (const int*)d_in[3];
    const int*  mention_idx= (const int*)d_in[4];
    const void* W_head     = d_in[5];
    const void* b_head     = d_in[6];
    const void* W_tail     = d_in[7];
    const void* b_tail     = d_in[8];
    const void* W_rel      = d_in[9];
    const void* b_rel      = d_in[10];
    const void* W_fh       = d_in[11];
    const void* W_ft       = d_in[12];
    const void* b_f        = d_in[13];
    const void* W_unet     = d_in[14];
    const void* b_unet     = d_in[15];
    const void* W_mlp      = d_in[16];
    const void* b_mlp      = d_in[17];
    const void* W_bil      = d_in[18];
    const void* b_bil      = d_in[19];

    float* w = (float*)d_ws;
    unsigned short* mentb = (unsigned short*)(w + 64);       // 98304 fl
    float* ent_emb  = w + 98368;                             // 49152
    // (ent_att slot unused now)
    unsigned short* htb = (unsigned short*)(w + 540736);     // 131072 fl
    float* rs       = w + 671808;                            // 393216
    float* hz       = w + 1065024;                           // 393216
    float* tz       = w + 1458240;                           // 393216
    float* mu       = w + 1851456;                           // 131072
    unsigned short* seqT  = (unsigned short*)(w + 1982784);  // 393216 fl
    unsigned short* WhT   = (unsigned short*)(w + 2376000);  // 589824 fl
    unsigned short* WtT   = (unsigned short*)(w + 2965824);  // 589824 fl
    unsigned short* WfhT  = (unsigned short*)(w + 3555648);  // 294912 fl
    unsigned short* WftT  = (unsigned short*)(w + 3850560);  // 294912 fl
    unsigned short* WunetT= (unsigned short*)(w + 4145472);  // 49152 fl
    unsigned short* WmlpT = (unsigned short*)(w + 4194624);  // 49152 fl
    unsigned short* Tbh   = (unsigned short*)(w + 4243776);  // 98304 fl
    unsigned short* Tbt   = (unsigned short*)(w + 4342080);  // 98304 fl
    unsigned short* hcatb = (unsigned short*)(w + 4440384);  // 393216 fl
    unsigned short* tcatb = (unsigned short*)(w + 4833600);  // 393216 fl
    unsigned short* WBt   = (unsigned short*)(w + 5226816);  // 2752512 fl (fragment-major tiles)
    float* partial  = w + 7979328;                           // used: 512*48*128 = 3145728
    float* c23p     = w + 11200000;                          // 3104 fl (in partial slot's tail)
    float* W_bilF   = w + 11649344;                          // 28227 fl

    // 1. prep: c23 partials (z=0) + W_rel conv (z=1) + transposes (z=2..9) + W_bilF (z=10)
    {
        PrepArgs a = {};
        const void* srcs[8] = {W_head, W_tail, W_fh, W_ft, W_unet, W_mlp, seq, seq};
        long offs[8]   = {0,0,0,0,0,0,0,393216};
        int Ks[8]      = {1536,1536,768,768,768,768,512,512};
        int Ncols8[8]  = {768,768,768,768,97,97,768,768};
        int Npads[8]   = {768,768,768,768,128,128,768,768};
        unsigned short* dsts[8] = {WhT, WtT, WfhT, WftT, WunetT, WmlpT, seqT, seqT+393216};
        for (int z = 0; z < 8; z++) {
            a.src[z]=srcs[z]; a.off[z]=offs[z]; a.K[z]=Ks[z];
            a.Ncols[z]=Ncols8[z]; a.Npad[z]=Npads[z]; a.dst[z]=dsts[z];
        }
        a.W_bil = W_bil; a.W_bilF = W_bilF;
        a.b_f = b_f; a.W_unet = W_unet; a.b_unet = b_unet;
        a.W_mlp = W_mlp; a.b_mlp = b_mlp; a.c23p = c23p;
        a.W_rel = W_rel; a.WBt = WBt;
        a.seqd = seq;
        prep_kernel<<<dim3(48, 16, 11), 256, 0, stream>>>(a);
    }
    // 2. ghatt: ht_att direct-from-attn (512 blocks) + ment gather (64 blocks)
    ghatt_kernel<<<512 + 64, 256, 0, stream>>>(seq, attn, entity_pos, hts, mentb, ent_emb, htb);
    // 3. gemmA: rs (z=0,1) + T_{h,t} (z=2,3)
    {
        MfmaJob ga = {};
        ga.seqd = seq;
        for (int z = 0; z < 2; z++) {
            ga.A[z] = htb + (long)z*256*512; ga.Bt[z] = seqT + (long)z*393216;
            ga.bias[z] = nullptr; ga.C[z] = rs + (long)z*256*768;
            ga.K[z] = 512; ga.ldc[z] = 768; ga.act[z] = 0; ga.obf[z] = 0;
            ga.Mt[z] = 256; ga.Nt[z] = 768;
        }
        ga.A[2] = mentb; ga.Bt[2] = WfhT; ga.bias[2] = nullptr; ga.C[2] = Tbh;
        ga.K[2] = 768; ga.ldc[2] = 768; ga.act[2] = 0; ga.obf[2] = 1;
        ga.Mt[2] = 256; ga.Nt[2] = 768;
        ga.A[3] = mentb; ga.Bt[3] = WftT; ga.bias[3] = nullptr; ga.C[3] = Tbt;
        ga.K[3] = 768; ga.ldc[3] = 768; ga.act[3] = 0; ga.obf[3] = 1;
        ga.Mt[3] = 256; ga.Nt[3] = 768;
        mfma_nt2_kernel<<<dim3(8, 24, 4), 256, 0, stream>>>(ga);
    }
    // 4. concatenated inputs (bf16)
    catb_kernel<<<N_, 256, 0, stream>>>(ent_emb, rs, hts, hcatb, tcatb);
    // 5. gemmBC: hz/tz (z=0,1) + mu (z=2..5, rides along via M/N early-exit)
    {
        MfmaJob ga = {};
        ga.seqd = seq;
        ga.A[0] = hcatb; ga.Bt[0] = WhT; ga.bias[0] = b_head; ga.C[0] = hz;
        ga.A[1] = tcatb; ga.Bt[1] = WtT; ga.bias[1] = b_tail; ga.C[1] = tz;
        for (int z = 0; z < 2; z++) {
            ga.K[z] = 1536; ga.ldc[z] = 768; ga.act[z] = 1; ga.obf[z] = 0;
            ga.Mt[z] = 512; ga.Nt[z] = 768;
        }
        const unsigned short* As[4] = {Tbh, Tbt, Tbh, Tbt};
        const unsigned short* Bs[4] = {WunetT, WunetT, WmlpT, WmlpT};
        for (int q = 0; q < 4; q++) {
            int z = 2 + q;
            ga.A[z] = As[q]; ga.Bt[z] = Bs[q]; ga.bias[z] = nullptr;
            ga.C[z] = mu + q*32768;
            ga.K[z] = 768; ga.ldc[z] = 128; ga.act[z] = 0; ga.obf[z] = 0;
            ga.Mt[z] = 256; ga.Nt[z] = 128;
        }
        mfma_nt2_kernel<<<dim3(16, 24, 6), 256, 0, stream>>>(ga);
    }
    // 6. r1 partials via MFMA (v8: fragment-major, barrier-free)
    r1_mfma_kernel<<<dim3(KSPLIT_, 16), 256, 0, stream>>>(hz, tz, WBt, partial);
    // 7. fused reduce + r2/r3 + final projection
    r23out_kernel<<<N_, 128, 0, stream>>>(partial, b_rel, mu, c23p, hts, mention_idx,
                                          W_bilF, b_bil, d_out, seq);
}

// Round 11
// 211.680 us; speedup vs baseline: 1.1529x; 1.0189x over previous
//
#include <hip/hip_runtime.h>
#include <hip/hip_bf16.h>

// Problem constants
#define B_  2
#define L_  512
#define D_  768
#define H_  12
#define E_  32
#define M_  4
#define P_  256
#define EMB_ 768
#define BS_ 64
#define C_  97
#define N_  (B_*P_)   // 512

#define KTOT_    49152      // EMB*BS
#define CPAD_    112        // 97 padded to 7*16
#define KSPLIT_  48
#define KCHUNK_  (KTOT_/KSPLIT_)   // 1024, 16 ks-steps of 64
#define PSTR_    128        // partial chunk stride (floats): 512 B, cache-line exclusive
#define TILE_    (CPAD_*64) // 7168 ushorts = 14336 B per k-step tile of WBt (fragment-major)

typedef __hip_bfloat16 bf16;
typedef __attribute__((ext_vector_type(8))) short bf16x8;
typedef __attribute__((ext_vector_type(4))) float f32x4;
typedef __attribute__((ext_vector_type(8))) float f32x8;

__device__ inline float ldIn(const void* p, long idx, int isbf) {
    return isbf ? (float)((const bf16*)p)[idx] : ((const float*)p)[idx];
}

__device__ inline unsigned short f2bf(float f) {
    bf16 h = (bf16)f;
    return *(unsigned short*)&h;
}

// Per-wave inline dtype detection. bf16 N(0,1) never has (u>>7)&0xFF >= 140;
// fp32 low-halves are ~uniform -> ~45% hit rate; P(false bf16) ~ 5e-9.
__device__ inline int detect_bf(const void* seqd) {
    const unsigned short* u = (const unsigned short*)seqd;
    int lane = threadIdx.x & 63;
    unsigned short e = (u[lane] >> 7) & 0xFF;
    unsigned long long m = __ballot(e >= 140);
    return m == 0ull;
}

// ---------------- prep: z=0 c23 partials, z=1 W_rel fragment-major conv,
// z=2..9 transposes (VECTORIZED: bf16x8/float4 reads, uint4 writes),
// z=10 W_bil->f32.
struct PrepArgs {
    const void* src[8];
    long off[8];
    int K[8];
    int Ncols[8];
    int Npad[8];
    unsigned short* dst[8];
    const void* W_bil;  float* W_bilF;
    const void* b_f; const void* W_unet; const void* b_unet;
    const void* W_mlp; const void* b_mlp; float* c23p;
    const void* W_rel; unsigned short* WBt;
    const void* seqd;
};

union PrepSm {
    float T[32][65];                 // 8320 B
    unsigned short TW[CPAD_][72];    // 16128 B
};

__global__ void prep_kernel(PrepArgs a) {
    int isbf = detect_bf(a.seqd);
    int z = blockIdx.z;
    __shared__ PrepSm sm;
    int tid = threadIdx.x;
    if (z == 0) {
        // c23 partials: 16 blocks x 48 d-rows -> c23p[lin][2][97], summed in r23out
        int lin = blockIdx.y*48 + blockIdx.x;
        if (lin >= 16) return;
        int c = tid;
        if (c >= C_) return;
        float s2 = 0.f, s3 = 0.f;
        int d0 = lin*48;
        for (int i = 0; i < 48; i++) {
            int d = d0 + i;
            float bf = ldIn(a.b_f, d, isbf);
            s2 += bf * ldIn(a.W_unet, (long)d*C_ + c, isbf);
            s3 += bf * ldIn(a.W_mlp,  (long)d*C_ + c, isbf);
        }
        if (lin == 0) {
            s2 += ldIn(a.b_unet, c, isbf);
            s3 += ldIn(a.b_mlp,  c, isbf);
        }
        a.c23p[lin*194 + c]      = s2;
        a.c23p[lin*194 + 97 + c] = s3;
    } else if (z == 1) {
        // W_rel -> WBt FRAGMENT-MAJOR: per k-step tile t, item idx=(ct*2+h)*64+l
        // stores the 8 bf16 lane l of c-tile ct, k-half h consumes as MFMA B.
        int lin = blockIdx.y*48 + blockIdx.x;
        if (lin >= KTOT_/64) return;
        int k0 = lin * 64;
        for (int idx = tid; idx < 64*97; idx += 256) {
            int kk = idx / 97, c = idx % 97;
            sm.TW[c][kk] = f2bf(ldIn(a.W_rel, (long)(k0+kk)*C_ + c, isbf));
        }
        for (int idx = tid; idx < 15*64; idx += 256) {
            sm.TW[97 + (idx>>6)][idx & 63] = 0;
        }
        __syncthreads();
        unsigned short* tb = a.WBt + (long)lin*TILE_;
        for (int t = 0; t < 4; t++) {
            int idx = tid + t*256;      // < 896
            if (idx < 896) {
                int l  = idx & 63;
                int h  = (idx >> 6) & 1;
                int ct = idx >> 7;
                int row = ct*16 + (l & 15);
                int col = h*32 + (l >> 4)*8;
                *(uint4*)(tb + idx*8) = *(uint4*)&sm.TW[row][col];
            }
        }
    } else if (z <= 9) {
        int j = z - 2;
        int K = a.K[j], Ncols = a.Ncols[j], Npad = a.Npad[j];
        int k0 = blockIdx.x*32, n0 = blockIdx.y*64;
        if (k0 >= K || n0 >= Npad) return;
        const void* src = a.src[j];
        long off = a.off[j];
        unsigned short* dst = a.dst[j];
        // read: 32x64 tile, 8 consecutive cols per thread (vector when aligned)
        int r = tid >> 3, c8 = (tid & 7) * 8;
        if ((Ncols & 7) == 0) {
            long base = off + (long)(k0+r)*Ncols + n0 + c8;
            if (isbf) {
                unsigned short tmp[8];
                *(uint4*)tmp = *(const uint4*)((const unsigned short*)src + base);
                #pragma unroll
                for (int e = 0; e < 8; e++) {
                    bf16 hh = *(bf16*)&tmp[e];
                    sm.T[r][c8+e] = (float)hh;
                }
            } else {
                const float* sp = (const float*)src + base;
                float4 x = *(const float4*)sp;
                float4 y = *(const float4*)(sp + 4);
                sm.T[r][c8+0]=x.x; sm.T[r][c8+1]=x.y; sm.T[r][c8+2]=x.z; sm.T[r][c8+3]=x.w;
                sm.T[r][c8+4]=y.x; sm.T[r][c8+5]=y.y; sm.T[r][c8+6]=y.z; sm.T[r][c8+7]=y.w;
            }
        } else {
            #pragma unroll
            for (int e = 0; e < 8; e++) {
                int n = n0 + c8 + e;
                sm.T[r][c8+e] = (n < Ncols) ? ldIn(src, off + (long)(k0+r)*Ncols + n, isbf) : 0.f;
            }
        }
        __syncthreads();
        // write: thread handles row n0+nn, k-range k0+q8..+7 as one uint4
        int nn = tid >> 2, q8 = (tid & 3) * 8;
        unsigned short o[8];
        #pragma unroll
        for (int e = 0; e < 8; e++) o[e] = f2bf(sm.T[q8+e][nn]);
        *(uint4*)(dst + (long)(n0+nn)*K + k0 + q8) = *(uint4*)o;
    } else {
        int lin = blockIdx.y*48 + blockIdx.x;
        int idx = lin*256 + tid;
        if (idx < 291*C_) a.W_bilF[idx] = ldIn(a.W_bil, idx, isbf);
    }
}

// ---------------- ghatt: merged gather + htatt ----------------
__global__ void ghatt_kernel(const void* __restrict__ seq, const void* __restrict__ attn,
                             const int* __restrict__ entity_pos, const int* __restrict__ hts,
                             unsigned short* __restrict__ mentb, float* __restrict__ ent_emb,
                             unsigned short* __restrict__ htb) {
    int isbf = detect_bf(seq);
    if (blockIdx.x < 512) {
        int bp = blockIdx.x;
        int b = bp >> 8;
        int h_e = hts[bp*2+0], t_e = hts[bp*2+1];
        int ph[M_], pt[M_];
        for (int m = 0; m < M_; m++) {
            ph[m] = entity_pos[(b*E_ + h_e)*M_ + m] + 1;
            pt[m] = entity_pos[(b*E_ + t_e)*M_ + m] + 1;
        }
        __shared__ float red[256];
        float v[2];
        for (int t = 0; t < 2; t++) {
            int l = threadIdx.x + t*256;
            float s = 0.f;
            for (int h = 0; h < H_; h++) {
                long hb = ((long)(b*H_ + h))*L_;
                float ha = 0.f, ta = 0.f;
                for (int m = 0; m < M_; m++) {
                    ha += ldIn(attn, (hb + ph[m])*L_ + l, isbf);
                    ta += ldIn(attn, (hb + pt[m])*L_ + l, isbf);
                }
                s += ha * ta;
            }
            v[t] = s * (0.0625f / H_);   // 0.25^2 mention means / H
        }
        red[threadIdx.x] = v[0] + v[1];
        __syncthreads();
        for (int off = 128; off > 0; off >>= 1) {
            if (threadIdx.x < off) red[threadIdx.x] += red[threadIdx.x+off];
            __syncthreads();
        }
        float inv = 1.0f / (red[0] + 1e-5f);
        for (int t = 0; t < 2; t++) {
            int l = threadIdx.x + t*256;
            htb[(long)bp*L_ + l] = f2bf(v[t] * inv);
        }
    } else {
        int be = blockIdx.x - 512;     // 0..63
        int b = be >> 5;
        int pos[M_];
        for (int m = 0; m < M_; m++) pos[m] = entity_pos[be*M_+m] + 1;
        for (int d = threadIdx.x; d < D_; d += 256) {
            float x[M_];
            for (int m = 0; m < M_; m++) {
                x[m] = ldIn(seq, ((long)b*L_ + pos[m])*D_ + d, isbf);
                mentb[((long)be*M_ + m)*D_ + d] = f2bf(x[m]);
            }
            float mx = fmaxf(fmaxf(x[0],x[1]), fmaxf(x[2],x[3]));
            float s = expf(x[0]-mx)+expf(x[1]-mx)+expf(x[2]-mx)+expf(x[3]-mx);
            ent_emb[(long)be*D_ + d] = mx + logf(s);
        }
    }
}

// ---------------- catb: hcatb=[hs,rs], tcatb=[ts,rs] in bf16 ----------------
__global__ void catb_kernel(const float* __restrict__ ent_emb, const float* __restrict__ rs,
                            const int* __restrict__ hts,
                            unsigned short* __restrict__ hcatb, unsigned short* __restrict__ tcatb) {
    int n = blockIdx.x;             // 512
    int b = n >> 8;
    int h_e = hts[n*2+0], t_e = hts[n*2+1];
    const float* eh = ent_emb + (long)(b*E_ + h_e)*D_;
    const float* et = ent_emb + (long)(b*E_ + t_e)*D_;
    const float* r  = rs + (long)n*D_;
    for (int k = threadIdx.x; k < D_; k += 256) {
        hcatb[(long)n*1536 + k] = f2bf(eh[k]);
        tcatb[(long)n*1536 + k] = f2bf(et[k]);
        unsigned short rb = f2bf(r[k]);
        hcatb[(long)n*1536 + 768 + k] = rb;
        tcatb[(long)n*1536 + 768 + k] = rb;
    }
}

// ---------------- Generic MFMA GEMM, 32x32 tiles, BK=128 ----------------
// BK 64->128: stage count (and the per-stage vmcnt(0)+barrier drain) halves.
// LDS 34.8 KB (2 dbuf x 2 ops x 32 x 136 ushorts), still 4 blocks/CU.
struct MfmaJob {
    const unsigned short* A[8];
    const unsigned short* Bt[8];
    const void* bias[8];
    void* C[8];
    const void* seqd;
    int K[8];
    int ldc[8];
    int act[8];
    int obf[8];
    int Mt[8];
    int Nt[8];
};

__global__ void mfma_nt2_kernel(MfmaJob args) {
    int z = blockIdx.z;
    int m0 = blockIdx.x*32, n0 = blockIdx.y*32;
    if (m0 >= args.Mt[z] || n0 >= args.Nt[z]) return;
    int isbf = detect_bf(args.seqd);
    const unsigned short* A  = args.A[z];
    const unsigned short* Bt = args.Bt[z];
    const void* bias = args.bias[z];
    void* C = args.C[z];
    int K = args.K[z], ldc = args.ldc[z], act = args.act[z], obf = args.obf[z];
    __shared__ unsigned short Al[2][32][136];
    __shared__ unsigned short Btl[2][32][136];
    int tid = threadIdx.x, wave = tid>>6, lane = tid&63;
    int lm = lane&15, lq = lane>>4;
    int rowg = wave>>1, cgrp = wave&1;   // wave -> (row half, col half)
    int rr = tid >> 3;                // 0..31
    int kc = (tid & 7) * 16;          // col offset in ushorts (128 cols/stage)
    uint4 ra0, ra1, rb0, rb1;

    ra0 = *(const uint4*)(A  + (long)(m0+rr)*K + kc);
    ra1 = *(const uint4*)(A  + (long)(m0+rr)*K + kc + 8);
    rb0 = *(const uint4*)(Bt + (long)(n0+rr)*K + kc);
    rb1 = *(const uint4*)(Bt + (long)(n0+rr)*K + kc + 8);
    *(uint4*)&Al[0][rr][kc]    = ra0;
    *(uint4*)&Al[0][rr][kc+8]  = ra1;
    *(uint4*)&Btl[0][rr][kc]   = rb0;
    *(uint4*)&Btl[0][rr][kc+8] = rb1;

    int nst = K >> 7;                 // K in {512,768,1536}, all mult of 128
    f32x4 acc = {};
    for (int ks = 0; ks < nst; ks++) {
        __syncthreads();
        if (ks+1 < nst) {
            int kk = (ks+1) << 7;
            ra0 = *(const uint4*)(A  + (long)(m0+rr)*K + kk + kc);
            ra1 = *(const uint4*)(A  + (long)(m0+rr)*K + kk + kc + 8);
            rb0 = *(const uint4*)(Bt + (long)(n0+rr)*K + kk + kc);
            rb1 = *(const uint4*)(Bt + (long)(n0+rr)*K + kk + kc + 8);
        }
        int cb = ks & 1;
        #pragma unroll
        for (int half = 0; half < 4; half++) {
            bf16x8 af  = *(bf16x8*)&Al[cb][rowg*16+lm][half*32+lq*8];
            bf16x8 bfr = *(bf16x8*)&Btl[cb][cgrp*16+lm][half*32+lq*8];
            acc = __builtin_amdgcn_mfma_f32_16x16x32_bf16(af, bfr, acc, 0, 0, 0);
        }
        if (ks+1 < nst) {
            int nb = (ks+1) & 1;
            *(uint4*)&Al[nb][rr][kc]    = ra0;
            *(uint4*)&Al[nb][rr][kc+8]  = ra1;
            *(uint4*)&Btl[nb][rr][kc]   = rb0;
            *(uint4*)&Btl[nb][rr][kc+8] = rb1;
        }
    }
    int n = n0 + cgrp*16 + lm;
    float bia = bias ? ldIn(bias, n, isbf) : 0.f;
    #pragma unroll
    for (int r = 0; r < 4; r++) {
        int m = m0 + rowg*16 + lq*4 + r;
        float v = acc[r] + bia;
        if (act == 1) v = tanhf(v);
        if (obf) ((unsigned short*)C)[(long)m*ldc + n] = f2bf(v);
        else     ((float*)C)[(long)m*ldc + n] = v;
    }
}

// ================= r1 via MFMA (v8, unchanged) =================
__global__ __launch_bounds__(256, 3)
void r1_mfma_kernel(const float* __restrict__ hz, const float* __restrict__ tz,
                    const unsigned short* __restrict__ WBt,
                    float* __restrict__ partial) {
    __shared__ float hzL[32][17];
    int kz = blockIdx.x;
    int nb0 = blockIdx.y * 32;
    int gk0 = kz * 16;               // global k-step base
    int gi0 = kz * 16;               // hz col base
    int g0 = (kz * KCHUNK_) >> 12;   // tz group, fixed for the whole chunk
    int tid = threadIdx.x;
    int wave = tid >> 6, lane = tid & 63;
    int lm = lane & 15;
    int ctb = wave * 2;              // c-tile base: 0,2,4,6
    int nct = (wave < 3) ? 2 : 1;    // c-tiles this wave computes

    {
        int r = tid >> 3, q = (tid & 7) * 2;
        float2 v = *(const float2*)(hz + (long)(nb0 + r)*EMB_ + gi0 + q);
        hzL[r][q] = v.x; hzL[r][q+1] = v.y;
    }
    int lq = lane >> 4;
    f32x8 tza[2], tzb[2];            // [rowg], halves 0/1
    #pragma unroll
    for (int rg = 0; rg < 2; rg++) {
        const float* tp = tz + (long)(nb0 + rg*16 + lm)*EMB_ + g0*64;
        float4 x0 = *(const float4*)(tp + lq*8);
        float4 y0 = *(const float4*)(tp + lq*8 + 4);
        float4 x1 = *(const float4*)(tp + 32 + lq*8);
        float4 y1 = *(const float4*)(tp + 32 + lq*8 + 4);
        tza[rg][0]=x0.x; tza[rg][1]=x0.y; tza[rg][2]=x0.z; tza[rg][3]=x0.w;
        tza[rg][4]=y0.x; tza[rg][5]=y0.y; tza[rg][6]=y0.z; tza[rg][7]=y0.w;
        tzb[rg][0]=x1.x; tzb[rg][1]=x1.y; tzb[rg][2]=x1.z; tzb[rg][3]=x1.w;
        tzb[rg][4]=y1.x; tzb[rg][5]=y1.y; tzb[rg][6]=y1.z; tzb[rg][7]=y1.w;
    }
    __syncthreads();   // hzL ready; ONLY barrier in the kernel

    const unsigned short* wb = WBt + (long)gk0*TILE_ + lane*8;

    f32x4 acc[2][2] = {};            // [ct][rowg]
    bf16x8 cb[2][2];                 // [ct][h] current B-frags
    #pragma unroll
    for (int ct = 0; ct < 2; ct++)
        if (ct < nct)
            #pragma unroll
            for (int h = 0; h < 2; h++)
                cb[ct][h] = *(const bf16x8*)(wb + ((ctb+ct)*2 + h)*512);

    #pragma unroll 2
    for (int ks = 0; ks < KCHUNK_/64; ks++) {
        bf16x8 nbuf[2][2];
        if (ks+1 < KCHUNK_/64) {
            const unsigned short* wn = wb + (long)(ks+1)*TILE_;
            #pragma unroll
            for (int ct = 0; ct < 2; ct++)
                if (ct < nct)
                    #pragma unroll
                    for (int h = 0; h < 2; h++)
                        nbuf[ct][h] = *(const bf16x8*)(wn + ((ctb+ct)*2 + h)*512);
        }
        float hv0 = hzL[lm][ks];
        float hv1 = hzL[16 + lm][ks];
        unsigned short o00[8], o01[8], o10[8], o11[8];
        #pragma unroll
        for (int e = 0; e < 8; e++) {
            o00[e] = f2bf(tza[0][e] * hv0);
            o01[e] = f2bf(tzb[0][e] * hv0);
            o10[e] = f2bf(tza[1][e] * hv1);
            o11[e] = f2bf(tzb[1][e] * hv1);
        }
        bf16x8 a00 = *(bf16x8*)o00, a01 = *(bf16x8*)o01;
        bf16x8 a10 = *(bf16x8*)o10, a11 = *(bf16x8*)o11;
        #pragma unroll
        for (int ct = 0; ct < 2; ct++) {
            if (ct < nct) {
                acc[ct][0] = __builtin_amdgcn_mfma_f32_16x16x32_bf16(a00, cb[ct][0], acc[ct][0], 0, 0, 0);
                acc[ct][0] = __builtin_amdgcn_mfma_f32_16x16x32_bf16(a01, cb[ct][1], acc[ct][0], 0, 0, 0);
                acc[ct][1] = __builtin_amdgcn_mfma_f32_16x16x32_bf16(a10, cb[ct][0], acc[ct][1], 0, 0, 0);
                acc[ct][1] = __builtin_amdgcn_mfma_f32_16x16x32_bf16(a11, cb[ct][1], acc[ct][1], 0, 0, 0);
            }
        }
        if (ks+1 < KCHUNK_/64) {
            #pragma unroll
            for (int ct = 0; ct < 2; ct++)
                if (ct < nct)
                    #pragma unroll
                    for (int h = 0; h < 2; h++)
                        cb[ct][h] = nbuf[ct][h];
        }
    }
    #pragma unroll
    for (int ct = 0; ct < 2; ct++) {
        if (ct < nct || wave == 3) {
            int c = (ctb + ct)*16 + lm;
            #pragma unroll
            for (int rg = 0; rg < 2; rg++) {
                #pragma unroll
                for (int r = 0; r < 4; r++) {
                    int nl = rg*16 + lq*4 + r;
                    float v = (ct < nct) ? acc[ct][rg][r] : 0.f;
                    partial[((long)(nb0+nl)*KSPLIT_ + kz)*PSTR_ + c] = v;
                }
            }
        }
    }
}

// ---------------- fused: r1 streaming reduce + r2/r3 LSE + final projection ----------------
__global__ void r23out_kernel(const float* __restrict__ partial, const void* __restrict__ b_rel,
                              const float* __restrict__ mu, const float* __restrict__ c23p,
                              const int* __restrict__ hts, const int* __restrict__ mention_idx,
                              const float* __restrict__ W_bilF, const void* __restrict__ b_bil,
                              void* __restrict__ out, const void* __restrict__ seqd) {
    int bp = blockIdx.x;
    int b = bp >> 8;
    int c = threadIdx.x;
    int isbf = detect_bf(seqd);
    __shared__ float row[292];
    if (c < C_) {
        const float* pr = partial + (long)bp*KSPLIT_*PSTR_;
        float r1v = 0.f;
        #pragma unroll 8
        for (int kz = 0; kz < KSPLIT_; kz++)
            r1v += pr[kz*PSTR_ + c];
        r1v += ldIn(b_rel, c, isbf);
        int h_e = hts[bp*2+0], t_e = hts[bp*2+1];
        const float* mu2h = mu;
        const float* mu2t = mu + 32768;
        const float* mu3h = mu + 65536;
        const float* mu3t = mu + 98304;
        float ah2[4], at2[4], ah3[4], at3[4];
        for (int m = 0; m < 4; m++) {
            int emh = mention_idx[(b*E_ + h_e)*M_ + m];
            int emt = mention_idx[(b*E_ + t_e)*M_ + m];
            ah2[m] = mu2h[(long)(b*128 + emh)*128 + c];
            ah3[m] = mu3h[(long)(b*128 + emh)*128 + c];
            at2[m] = mu2t[(long)(b*128 + emt)*128 + c];
            at3[m] = mu3t[(long)(b*128 + emt)*128 + c];
        }
        float c2 = 0.f, c3 = 0.f;
        #pragma unroll
        for (int j = 0; j < 16; j++) {
            c2 += c23p[j*194 + c];
            c3 += c23p[j*194 + 97 + c];
        }
        float v2[16], v3[16];
        int q = 0;
        for (int i = 0; i < 4; i++) {
            for (int j = 0; j < 4; j++, q++) {
                float x2 = ah2[i] + at2[j] + c2;
                v2[q] = tanhf(x2);
                float x3 = ah3[i] + at3[j] + c3;
                float t = tanhf(0.7978845608028654f * (x3 + 0.044715f*x3*x3*x3));
                v3[q] = 0.5f * x3 * (1.0f + t);
            }
        }
        float m2 = v2[0], m3 = v3[0];
        for (q = 1; q < 16; q++) { m2 = fmaxf(m2, v2[q]); m3 = fmaxf(m3, v3[q]); }
        float s2 = 0.f, s3 = 0.f;
        for (q = 0; q < 16; q++) { s2 += expf(v2[q]-m2); s3 += expf(v3[q]-m3); }
        row[c]        = r1v;
        row[C_ + c]   = m2 + logf(s2);
        row[2*C_ + c] = m3 + logf(s3);
    }
    __syncthreads();
    if (c >= C_) return;
    float a0 = 0.f, a1 = 0.f, a2 = 0.f, a3 = 0.f;
    #pragma unroll 4
    for (int k = 0; k < 288; k += 4) {
        a0 += row[k+0] * W_bilF[(k+0)*C_ + c];
        a1 += row[k+1] * W_bilF[(k+1)*C_ + c];
        a2 += row[k+2] * W_bilF[(k+2)*C_ + c];
        a3 += row[k+3] * W_bilF[(k+3)*C_ + c];
    }
    a0 += row[288] * W_bilF[288*C_ + c];
    a1 += row[289] * W_bilF[289*C_ + c];
    a2 += row[290] * W_bilF[290*C_ + c];
    float v = a0 + a1 + a2 + a3 + ldIn(b_bil, c, isbf);
    if (isbf) ((bf16*)out)[(long)bp*C_ + c] = (bf16)v;
    else      ((float*)out)[(long)bp*C_ + c] = v;
}

extern "C" void kernel_launch(void* const* d_in, const int* in_sizes, int n_in,
                              void* d_out, int out_size, void* d_ws, size_t ws_size,
                              hipStream_t stream) {
    const void* seq        = d_in[0];
    const void* attn       = d_in[1];
    const int*  entity_pos = (const int*)d_in[2];
    const int*  hts        = (const int*)d_in[3];
    const int*  mention_idx= (const int*)d_in[4];
    const void* W_head     = d_in[5];
    const void* b_head     = d_in[6];
    const void* W_tail     = d_in[7];
    const void* b_tail     = d_in[8];
    const void* W_rel      = d_in[9];
    const void* b_rel      = d_in[10];
    const void* W_fh       = d_in[11];
    const void* W_ft       = d_in[12];
    const void* b_f        = d_in[13];
    const void* W_unet     = d_in[14];
    const void* b_unet     = d_in[15];
    const void* W_mlp      = d_in[16];
    const void* b_mlp      = d_in[17];
    const void* W_bil      = d_in[18];
    const void* b_bil      = d_in[19];

    float* w = (float*)d_ws;
    unsigned short* mentb = (unsigned short*)(w + 64);       // 98304 fl
    float* ent_emb  = w + 98368;                             // 49152
    unsigned short* htb = (unsigned short*)(w + 540736);     // 131072 fl
    float* rs       = w + 671808;                            // 393216
    float* hz       = w + 1065024;                           // 393216
    float* tz       = w + 1458240;                           // 393216
    float* mu       = w + 1851456;                           // 131072
    unsigned short* seqT  = (unsigned short*)(w + 1982784);  // 393216 fl
    unsigned short* WhT   = (unsigned short*)(w + 2376000);  // 589824 fl
    unsigned short* WtT   = (unsigned short*)(w + 2965824);  // 589824 fl
    unsigned short* WfhT  = (unsigned short*)(w + 3555648);  // 294912 fl
    unsigned short* WftT  = (unsigned short*)(w + 3850560);  // 294912 fl
    unsigned short* WunetT= (unsigned short*)(w + 4145472);  // 49152 fl
    unsigned short* WmlpT = (unsigned short*)(w + 4194624);  // 49152 fl
    unsigned short* Tbh   = (unsigned short*)(w + 4243776);  // 98304 fl
    unsigned short* Tbt   = (unsigned short*)(w + 4342080);  // 98304 fl
    unsigned short* hcatb = (unsigned short*)(w + 4440384);  // 393216 fl
    unsigned short* tcatb = (unsigned short*)(w + 4833600);  // 393216 fl
    unsigned short* WBt   = (unsigned short*)(w + 5226816);  // 2752512 fl (fragment-major tiles)
    float* partial  = w + 7979328;                           // used: 512*48*128 = 3145728
    float* c23p     = w + 11200000;                          // 3104 fl (in partial slot's tail)
    float* W_bilF   = w + 11649344;                          // 28227 fl

    // 1. prep: c23 partials (z=0) + W_rel conv (z=1) + transposes (z=2..9) + W_bilF (z=10)
    {
        PrepArgs a = {};
        const void* srcs[8] = {W_head, W_tail, W_fh, W_ft, W_unet, W_mlp, seq, seq};
        long offs[8]   = {0,0,0,0,0,0,0,393216};
        int Ks[8]      = {1536,1536,768,768,768,768,512,512};
        int Ncols8[8]  = {768,768,768,768,97,97,768,768};
        int Npads[8]   = {768,768,768,768,128,128,768,768};
        unsigned short* dsts[8] = {WhT, WtT, WfhT, WftT, WunetT, WmlpT, seqT, seqT+393216};
        for (int z = 0; z < 8; z++) {
            a.src[z]=srcs[z]; a.off[z]=offs[z]; a.K[z]=Ks[z];
            a.Ncols[z]=Ncols8[z]; a.Npad[z]=Npads[z]; a.dst[z]=dsts[z];
        }
        a.W_bil = W_bil; a.W_bilF = W_bilF;
        a.b_f = b_f; a.W_unet = W_unet; a.b_unet = b_unet;
        a.W_mlp = W_mlp; a.b_mlp = b_mlp; a.c23p = c23p;
        a.W_rel = W_rel; a.WBt = WBt;
        a.seqd = seq;
        prep_kernel<<<dim3(48, 16, 11), 256, 0, stream>>>(a);
    }
    // 2. ghatt: ht_att direct-from-attn (512 blocks) + ment gather (64 blocks)
    ghatt_kernel<<<512 + 64, 256, 0, stream>>>(seq, attn, entity_pos, hts, mentb, ent_emb, htb);
    // 3. gemmA: rs (z=0,1) + T_{h,t} (z=2,3)
    {
        MfmaJob ga = {};
        ga.seqd = seq;
        for (int z = 0; z < 2; z++) {
            ga.A[z] = htb + (long)z*256*512; ga.Bt[z] = seqT + (long)z*393216;
            ga.bias[z] = nullptr; ga.C[z] = rs + (long)z*256*768;
            ga.K[z] = 512; ga.ldc[z] = 768; ga.act[z] = 0; ga.obf[z] = 0;
            ga.Mt[z] = 256; ga.Nt[z] = 768;
        }
        ga.A[2] = mentb; ga.Bt[2] = WfhT; ga.bias[2] = nullptr; ga.C[2] = Tbh;
        ga.K[2] = 768; ga.ldc[2] = 768; ga.act[2] = 0; ga.obf[2] = 1;
        ga.Mt[2] = 256; ga.Nt[2] = 768;
        ga.A[3] = mentb; ga.Bt[3] = WftT; ga.bias[3] = nullptr; ga.C[3] = Tbt;
        ga.K[3] = 768; ga.ldc[3] = 768; ga.act[3] = 0; ga.obf[3] = 1;
        ga.Mt[3] = 256; ga.Nt[3] = 768;
        mfma_nt2_kernel<<<dim3(8, 24, 4), 256, 0, stream>>>(ga);
    }
    // 4. concatenated inputs (bf16)
    catb_kernel<<<N_, 256, 0, stream>>>(ent_emb, rs, hts, hcatb, tcatb);
    // 5. gemmBC: hz/tz (z=0,1) + mu (z=2..5, rides along via M/N early-exit)
    {
        MfmaJob ga = {};
        ga.seqd = seq;
        ga.A[0] = hcatb; ga.Bt[0] = WhT; ga.bias[0] = b_head; ga.C[0] = hz;
        ga.A[1] = tcatb; ga.Bt[1] = WtT; ga.bias[1] = b_tail; ga.C[1] = tz;
        for (int z = 0; z < 2; z++) {
            ga.K[z] = 1536; ga.ldc[z] = 768; ga.act[z] = 1; ga.obf[z] = 0;
            ga.Mt[z] = 512; ga.Nt[z] = 768;
        }
        const unsigned short* As[4] = {Tbh, Tbt, Tbh, Tbt};
        const unsigned short* Bs[4] = {WunetT, WunetT, WmlpT, WmlpT};
        for (int q = 0; q < 4; q++) {
            int z = 2 + q;
            ga.A[z] = As[q]; ga.Bt[z] = Bs[q]; ga.bias[z] = nullptr;
            ga.C[z] = mu + q*32768;
            ga.K[z] = 768; ga.ldc[z] = 128; ga.act[z] = 0; ga.obf[z] = 0;
            ga.Mt[z] = 256; ga.Nt[z] = 128;
        }
        mfma_nt2_kernel<<<dim3(16, 24, 6), 256, 0, stream>>>(ga);
    }
    // 6. r1 partials via MFMA (v8: fragment-major, barrier-free)
    r1_mfma_kernel<<<dim3(KSPLIT_, 16), 256, 0, stream>>>(hz, tz, WBt, partial);
    // 7. fused reduce + r2/r3 + final projection
    r23out_kernel<<<N_, 128, 0, stream>>>(partial, b_rel, mu, c23p, hts, mention_idx,
                                          W_bilF, b_bil, d_out, seq);
}

// Round 12
// 208.057 us; speedup vs baseline: 1.1729x; 1.0174x over previous
//
#include <hip/hip_runtime.h>
#include <hip/hip_bf16.h>

// Problem constants
#define B_  2
#define L_  512
#define D_  768
#define H_  12
#define E_  32
#define M_  4
#define P_  256
#define EMB_ 768
#define BS_ 64
#define C_  97
#define N_  (B_*P_)   // 512

#define KTOT_    49152      // EMB*BS
#define CPAD_    112        // 97 padded to 7*16
#define KSPLIT_  48
#define KCHUNK_  (KTOT_/KSPLIT_)   // 1024, 16 ks-steps of 64
#define PSTR_    128        // partial chunk stride (floats): 512 B, cache-line exclusive
#define TILE_    (CPAD_*64) // 7168 ushorts = 14336 B per k-step tile of WBt (fragment-major)

typedef __hip_bfloat16 bf16;
typedef __attribute__((ext_vector_type(8))) short bf16x8;
typedef __attribute__((ext_vector_type(4))) float f32x4;
typedef __attribute__((ext_vector_type(8))) float f32x8;

__device__ inline float ldIn(const void* p, long idx, int isbf) {
    return isbf ? (float)((const bf16*)p)[idx] : ((const float*)p)[idx];
}

__device__ inline unsigned short f2bf(float f) {
    bf16 h = (bf16)f;
    return *(unsigned short*)&h;
}

__device__ inline void cvt16(unsigned short* o, float4 a, float4 b, float4 c, float4 d) {
    o[0]=f2bf(a.x);  o[1]=f2bf(a.y);  o[2]=f2bf(a.z);  o[3]=f2bf(a.w);
    o[4]=f2bf(b.x);  o[5]=f2bf(b.y);  o[6]=f2bf(b.z);  o[7]=f2bf(b.w);
    o[8]=f2bf(c.x);  o[9]=f2bf(c.y);  o[10]=f2bf(c.z); o[11]=f2bf(c.w);
    o[12]=f2bf(d.x); o[13]=f2bf(d.y); o[14]=f2bf(d.z); o[15]=f2bf(d.w);
}

// Per-wave inline dtype detection. bf16 N(0,1) never has (u>>7)&0xFF >= 140;
// fp32 low-halves are ~uniform -> ~45% hit rate; P(false bf16) ~ 5e-9.
__device__ inline int detect_bf(const void* seqd) {
    const unsigned short* u = (const unsigned short*)seqd;
    int lane = threadIdx.x & 63;
    unsigned short e = (u[lane] >> 7) & 0xFF;
    unsigned long long m = __ballot(e >= 140);
    return m == 0ull;
}

// ---------------- prep+ghatt: z=0 c23 partials, z=1 W_rel fragment-major conv
// (LDS stride 80: 4-way write conflicts instead of 8-way), z=2..9 transposes
// (vectorized), z=10 W_bil->f32, z=11 ghatt (independent of prep -> overlaps).
struct PrepArgs {
    const void* src[8];
    long off[8];
    int K[8];
    int Ncols[8];
    int Npad[8];
    unsigned short* dst[8];
    const void* W_bil;  float* W_bilF;
    const void* b_f; const void* W_unet; const void* b_unet;
    const void* W_mlp; const void* b_mlp; float* c23p;
    const void* W_rel; unsigned short* WBt;
    const void* seqd;
    const void* attn; const int* entity_pos; const int* hts;
    unsigned short* mentb; float* ent_emb; unsigned short* htb;
};

union PrepSm {
    float T[32][65];                 // 8320 B
    unsigned short TW[CPAD_][80];    // 17920 B
    float red[256];                  // 1024 B (ghatt)
};

__global__ void prep_kernel(PrepArgs a) {
    int isbf = detect_bf(a.seqd);
    int z = blockIdx.z;
    __shared__ PrepSm sm;
    int tid = threadIdx.x;
    if (z == 0) {
        // c23 partials: 16 blocks x 48 d-rows -> c23p[lin][2][97], summed in r23out
        int lin = blockIdx.y*48 + blockIdx.x;
        if (lin >= 16) return;
        int c = tid;
        if (c >= C_) return;
        float s2 = 0.f, s3 = 0.f;
        int d0 = lin*48;
        for (int i = 0; i < 48; i++) {
            int d = d0 + i;
            float bf = ldIn(a.b_f, d, isbf);
            s2 += bf * ldIn(a.W_unet, (long)d*C_ + c, isbf);
            s3 += bf * ldIn(a.W_mlp,  (long)d*C_ + c, isbf);
        }
        if (lin == 0) {
            s2 += ldIn(a.b_unet, c, isbf);
            s3 += ldIn(a.b_mlp,  c, isbf);
        }
        a.c23p[lin*194 + c]      = s2;
        a.c23p[lin*194 + 97 + c] = s3;
    } else if (z == 1) {
        // W_rel -> WBt FRAGMENT-MAJOR: per k-step tile t, item idx=(ct*2+h)*64+l
        // stores the 8 bf16 lane l of c-tile ct, k-half h consumes as MFMA B.
        int lin = blockIdx.y*48 + blockIdx.x;
        if (lin >= KTOT_/64) return;
        int k0 = lin * 64;
        for (int idx = tid; idx < 64*97; idx += 256) {
            int kk = idx / 97, c = idx % 97;
            sm.TW[c][kk] = f2bf(ldIn(a.W_rel, (long)(k0+kk)*C_ + c, isbf));
        }
        for (int idx = tid; idx < 15*64; idx += 256) {
            sm.TW[97 + (idx>>6)][idx & 63] = 0;
        }
        __syncthreads();
        unsigned short* tb = a.WBt + (long)lin*TILE_;
        for (int t = 0; t < 4; t++) {
            int idx = tid + t*256;      // < 896
            if (idx < 896) {
                int l  = idx & 63;
                int h  = (idx >> 6) & 1;
                int ct = idx >> 7;
                int row = ct*16 + (l & 15);
                int col = h*32 + (l >> 4)*8;
                *(uint4*)(tb + idx*8) = *(uint4*)&sm.TW[row][col];
            }
        }
    } else if (z <= 9) {
        int j = z - 2;
        int K = a.K[j], Ncols = a.Ncols[j], Npad = a.Npad[j];
        int k0 = blockIdx.x*32, n0 = blockIdx.y*64;
        if (k0 >= K || n0 >= Npad) return;
        const void* src = a.src[j];
        long off = a.off[j];
        unsigned short* dst = a.dst[j];
        // read: 32x64 tile, 8 consecutive cols per thread (vector when aligned)
        int r = tid >> 3, c8 = (tid & 7) * 8;
        if ((Ncols & 7) == 0) {
            long base = off + (long)(k0+r)*Ncols + n0 + c8;
            if (isbf) {
                unsigned short tmp[8];
                *(uint4*)tmp = *(const uint4*)((const unsigned short*)src + base);
                #pragma unroll
                for (int e = 0; e < 8; e++) {
                    bf16 hh = *(bf16*)&tmp[e];
                    sm.T[r][c8+e] = (float)hh;
                }
            } else {
                const float* sp = (const float*)src + base;
                float4 x = *(const float4*)sp;
                float4 y = *(const float4*)(sp + 4);
                sm.T[r][c8+0]=x.x; sm.T[r][c8+1]=x.y; sm.T[r][c8+2]=x.z; sm.T[r][c8+3]=x.w;
                sm.T[r][c8+4]=y.x; sm.T[r][c8+5]=y.y; sm.T[r][c8+6]=y.z; sm.T[r][c8+7]=y.w;
            }
        } else {
            #pragma unroll
            for (int e = 0; e < 8; e++) {
                int n = n0 + c8 + e;
                sm.T[r][c8+e] = (n < Ncols) ? ldIn(src, off + (long)(k0+r)*Ncols + n, isbf) : 0.f;
            }
        }
        __syncthreads();
        // write: thread handles row n0+nn, k-range k0+q8..+7 as one uint4
        int nn = tid >> 2, q8 = (tid & 3) * 8;
        unsigned short o[8];
        #pragma unroll
        for (int e = 0; e < 8; e++) o[e] = f2bf(sm.T[q8+e][nn]);
        *(uint4*)(dst + (long)(n0+nn)*K + k0 + q8) = *(uint4*)o;
    } else if (z == 10) {
        int lin = blockIdx.y*48 + blockIdx.x;
        int idx = lin*256 + tid;
        if (idx < 291*C_) a.W_bilF[idx] = ldIn(a.W_bil, idx, isbf);
    } else {
        // z=11: ghatt (independent of all prep slices -> overlaps in this launch)
        int lin = blockIdx.y*48 + blockIdx.x;
        if (lin >= 576) return;
        if (lin < 512) {
            int bp = lin;
            int b = bp >> 8;
            int h_e = a.hts[bp*2+0], t_e = a.hts[bp*2+1];
            int ph[M_], pt[M_];
            for (int m = 0; m < M_; m++) {
                ph[m] = a.entity_pos[(b*E_ + h_e)*M_ + m] + 1;
                pt[m] = a.entity_pos[(b*E_ + t_e)*M_ + m] + 1;
            }
            float v[2];
            for (int t = 0; t < 2; t++) {
                int l = tid + t*256;
                float s = 0.f;
                for (int h = 0; h < H_; h++) {
                    long hb = ((long)(b*H_ + h))*L_;
                    float ha = 0.f, ta = 0.f;
                    for (int m = 0; m < M_; m++) {
                        ha += ldIn(a.attn, (hb + ph[m])*L_ + l, isbf);
                        ta += ldIn(a.attn, (hb + pt[m])*L_ + l, isbf);
                    }
                    s += ha * ta;
                }
                v[t] = s * (0.0625f / H_);   // 0.25^2 mention means / H
            }
            sm.red[tid] = v[0] + v[1];
            __syncthreads();
            for (int off = 128; off > 0; off >>= 1) {
                if (tid < off) sm.red[tid] += sm.red[tid+off];
                __syncthreads();
            }
            float inv = 1.0f / (sm.red[0] + 1e-5f);
            for (int t = 0; t < 2; t++) {
                int l = tid + t*256;
                a.htb[(long)bp*L_ + l] = f2bf(v[t] * inv);
            }
        } else {
            int be = lin - 512;     // 0..63
            int b = be >> 5;
            int pos[M_];
            for (int m = 0; m < M_; m++) pos[m] = a.entity_pos[be*M_+m] + 1;
            for (int d = tid; d < D_; d += 256) {
                float x[M_];
                for (int m = 0; m < M_; m++) {
                    x[m] = ldIn(a.seqd, ((long)b*L_ + pos[m])*D_ + d, isbf);
                    a.mentb[((long)be*M_ + m)*D_ + d] = f2bf(x[m]);
                }
                float mx = fmaxf(fmaxf(x[0],x[1]), fmaxf(x[2],x[3]));
                float s = expf(x[0]-mx)+expf(x[1]-mx)+expf(x[2]-mx)+expf(x[3]-mx);
                a.ent_emb[(long)be*D_ + d] = mx + logf(s);
            }
        }
    }
}

// ---------------- Generic MFMA GEMM, 32x32 tiles, BK=128 ----------------
// gath[z] != 0: A-operand gathered on the fly from fp32 sources: rows are
// ent_emb[b][hts[m]] for k<768 and rs[m] for k>=768 (the catb concat, fused).
// BK=128 means the 768-boundary falls exactly on stage 6 -> branch-free stages.
struct MfmaJob {
    const unsigned short* A[8];
    const unsigned short* Bt[8];
    const void* bias[8];
    void* C[8];
    const void* seqd;
    const int* hts;
    const float* ent_emb;
    const float* rsrc;
    int K[8];
    int ldc[8];
    int act[8];
    int obf[8];
    int Mt[8];
    int Nt[8];
    int gath[8];   // 0 none, 1 gather h, 2 gather t
};

__global__ void mfma_nt2_kernel(MfmaJob args) {
    int z = blockIdx.z;
    int m0 = blockIdx.x*32, n0 = blockIdx.y*32;
    if (m0 >= args.Mt[z] || n0 >= args.Nt[z]) return;
    int isbf = detect_bf(args.seqd);
    const unsigned short* A  = args.A[z];
    const unsigned short* Bt = args.Bt[z];
    const void* bias = args.bias[z];
    void* C = args.C[z];
    int K = args.K[z], ldc = args.ldc[z], act = args.act[z], obf = args.obf[z];
    int gmode = args.gath[z];
    __shared__ unsigned short Al[2][32][136];
    __shared__ unsigned short Btl[2][32][136];
    int tid = threadIdx.x, wave = tid>>6, lane = tid&63;
    int lm = lane&15, lq = lane>>4;
    int rowg = wave>>1, cgrp = wave&1;   // wave -> (row half, col half)
    int rr = tid >> 3;                // 0..31
    int kc = (tid & 7) * 16;          // col offset in elements (128 cols/stage)
    const float *gh = nullptr, *gr = nullptr;
    if (gmode) {
        int m = m0 + rr, b = m >> 8;
        int ent = args.hts[m*2 + (gmode-1)];
        gh = args.ent_emb + (long)(b*E_ + ent)*D_ + kc;
        gr = args.rsrc + (long)m*EMB_ + kc;
    }
    uint4 ra0, ra1, rb0, rb1;
    float4 fa0, fa1, fa2, fa3;

    if (gmode) {
        fa0 = *(const float4*)gh;      fa1 = *(const float4*)(gh+4);
        fa2 = *(const float4*)(gh+8);  fa3 = *(const float4*)(gh+12);
        unsigned short o[16];
        cvt16(o, fa0, fa1, fa2, fa3);
        *(uint4*)&Al[0][rr][kc]   = *(uint4*)o;
        *(uint4*)&Al[0][rr][kc+8] = *(uint4*)(o+8);
    } else {
        ra0 = *(const uint4*)(A + (long)(m0+rr)*K + kc);
        ra1 = *(const uint4*)(A + (long)(m0+rr)*K + kc + 8);
        *(uint4*)&Al[0][rr][kc]   = ra0;
        *(uint4*)&Al[0][rr][kc+8] = ra1;
    }
    rb0 = *(const uint4*)(Bt + (long)(n0+rr)*K + kc);
    rb1 = *(const uint4*)(Bt + (long)(n0+rr)*K + kc + 8);
    *(uint4*)&Btl[0][rr][kc]   = rb0;
    *(uint4*)&Btl[0][rr][kc+8] = rb1;

    int nst = K >> 7;                 // K in {512,768,1536}, all mult of 128
    f32x4 acc = {};
    for (int ks = 0; ks < nst; ks++) {
        __syncthreads();
        if (ks+1 < nst) {
            int kk = (ks+1) << 7;
            if (gmode) {
                const float* s = (kk < D_) ? (gh + kk) : (gr + kk - D_);
                fa0 = *(const float4*)s;      fa1 = *(const float4*)(s+4);
                fa2 = *(const float4*)(s+8);  fa3 = *(const float4*)(s+12);
            } else {
                ra0 = *(const uint4*)(A + (long)(m0+rr)*K + kk + kc);
                ra1 = *(const uint4*)(A + (long)(m0+rr)*K + kk + kc + 8);
            }
            rb0 = *(const uint4*)(Bt + (long)(n0+rr)*K + kk + kc);
            rb1 = *(const uint4*)(Bt + (long)(n0+rr)*K + kk + kc + 8);
        }
        int cb = ks & 1;
        #pragma unroll
        for (int half = 0; half < 4; half++) {
            bf16x8 af  = *(bf16x8*)&Al[cb][rowg*16+lm][half*32+lq*8];
            bf16x8 bfr = *(bf16x8*)&Btl[cb][cgrp*16+lm][half*32+lq*8];
            acc = __builtin_amdgcn_mfma_f32_16x16x32_bf16(af, bfr, acc, 0, 0, 0);
        }
        if (ks+1 < nst) {
            int nb = (ks+1) & 1;
            if (gmode) {
                unsigned short o[16];
                cvt16(o, fa0, fa1, fa2, fa3);
                *(uint4*)&Al[nb][rr][kc]   = *(uint4*)o;
                *(uint4*)&Al[nb][rr][kc+8] = *(uint4*)(o+8);
            } else {
                *(uint4*)&Al[nb][rr][kc]   = ra0;
                *(uint4*)&Al[nb][rr][kc+8] = ra1;
            }
            *(uint4*)&Btl[nb][rr][kc]   = rb0;
            *(uint4*)&Btl[nb][rr][kc+8] = rb1;
        }
    }
    int n = n0 + cgrp*16 + lm;
    float bia = bias ? ldIn(bias, n, isbf) : 0.f;
    #pragma unroll
    for (int r = 0; r < 4; r++) {
        int m = m0 + rowg*16 + lq*4 + r;
        float v = acc[r] + bia;
        if (act == 1) v = tanhf(v);
        if (obf) ((unsigned short*)C)[(long)m*ldc + n] = f2bf(v);
        else     ((float*)C)[(long)m*ldc + n] = v;
    }
}

// ================= r1 via MFMA (v8, unchanged) =================
__global__ __launch_bounds__(256, 3)
void r1_mfma_kernel(const float* __restrict__ hz, const float* __restrict__ tz,
                    const unsigned short* __restrict__ WBt,
                    float* __restrict__ partial) {
    __shared__ float hzL[32][17];
    int kz = blockIdx.x;
    int nb0 = blockIdx.y * 32;
    int gk0 = kz * 16;               // global k-step base
    int gi0 = kz * 16;               // hz col base
    int g0 = (kz * KCHUNK_) >> 12;   // tz group, fixed for the whole chunk
    int tid = threadIdx.x;
    int wave = tid >> 6, lane = tid & 63;
    int lm = lane & 15;
    int ctb = wave * 2;              // c-tile base: 0,2,4,6
    int nct = (wave < 3) ? 2 : 1;    // c-tiles this wave computes

    {
        int r = tid >> 3, q = (tid & 7) * 2;
        float2 v = *(const float2*)(hz + (long)(nb0 + r)*EMB_ + gi0 + q);
        hzL[r][q] = v.x; hzL[r][q+1] = v.y;
    }
    int lq = lane >> 4;
    f32x8 tza[2], tzb[2];            // [rowg], halves 0/1
    #pragma unroll
    for (int rg = 0; rg < 2; rg++) {
        const float* tp = tz + (long)(nb0 + rg*16 + lm)*EMB_ + g0*64;
        float4 x0 = *(const float4*)(tp + lq*8);
        float4 y0 = *(const float4*)(tp + lq*8 + 4);
        float4 x1 = *(const float4*)(tp + 32 + lq*8);
        float4 y1 = *(const float4*)(tp + 32 + lq*8 + 4);
        tza[rg][0]=x0.x; tza[rg][1]=x0.y; tza[rg][2]=x0.z; tza[rg][3]=x0.w;
        tza[rg][4]=y0.x; tza[rg][5]=y0.y; tza[rg][6]=y0.z; tza[rg][7]=y0.w;
        tzb[rg][0]=x1.x; tzb[rg][1]=x1.y; tzb[rg][2]=x1.z; tzb[rg][3]=x1.w;
        tzb[rg][4]=y1.x; tzb[rg][5]=y1.y; tzb[rg][6]=y1.z; tzb[rg][7]=y1.w;
    }
    __syncthreads();   // hzL ready; ONLY barrier in the kernel

    const unsigned short* wb = WBt + (long)gk0*TILE_ + lane*8;

    f32x4 acc[2][2] = {};            // [ct][rowg]
    bf16x8 cb[2][2];                 // [ct][h] current B-frags
    #pragma unroll
    for (int ct = 0; ct < 2; ct++)
        if (ct < nct)
            #pragma unroll
            for (int h = 0; h < 2; h++)
                cb[ct][h] = *(const bf16x8*)(wb + ((ctb+ct)*2 + h)*512);

    #pragma unroll 2
    for (int ks = 0; ks < KCHUNK_/64; ks++) {
        bf16x8 nbuf[2][2];
        if (ks+1 < KCHUNK_/64) {
            const unsigned short* wn = wb + (long)(ks+1)*TILE_;
            #pragma unroll
            for (int ct = 0; ct < 2; ct++)
                if (ct < nct)
                    #pragma unroll
                    for (int h = 0; h < 2; h++)
                        nbuf[ct][h] = *(const bf16x8*)(wn + ((ctb+ct)*2 + h)*512);
        }
        float hv0 = hzL[lm][ks];
        float hv1 = hzL[16 + lm][ks];
        unsigned short o00[8], o01[8], o10[8], o11[8];
        #pragma unroll
        for (int e = 0; e < 8; e++) {
            o00[e] = f2bf(tza[0][e] * hv0);
            o01[e] = f2bf(tzb[0][e] * hv0);
            o10[e] = f2bf(tza[1][e] * hv1);
            o11[e] = f2bf(tzb[1][e] * hv1);
        }
        bf16x8 a00 = *(bf16x8*)o00, a01 = *(bf16x8*)o01;
        bf16x8 a10 = *(bf16x8*)o10, a11 = *(bf16x8*)o11;
        #pragma unroll
        for (int ct = 0; ct < 2; ct++) {
            if (ct < nct) {
                acc[ct][0] = __builtin_amdgcn_mfma_f32_16x16x32_bf16(a00, cb[ct][0], acc[ct][0], 0, 0, 0);
                acc[ct][0] = __builtin_amdgcn_mfma_f32_16x16x32_bf16(a01, cb[ct][1], acc[ct][0], 0, 0, 0);
                acc[ct][1] = __builtin_amdgcn_mfma_f32_16x16x32_bf16(a10, cb[ct][0], acc[ct][1], 0, 0, 0);
                acc[ct][1] = __builtin_amdgcn_mfma_f32_16x16x32_bf16(a11, cb[ct][1], acc[ct][1], 0, 0, 0);
            }
        }
        if (ks+1 < KCHUNK_/64) {
            #pragma unroll
            for (int ct = 0; ct < 2; ct++)
                if (ct < nct)
                    #pragma unroll
                    for (int h = 0; h < 2; h++)
                        cb[ct][h] = nbuf[ct][h];
        }
    }
    #pragma unroll
    for (int ct = 0; ct < 2; ct++) {
        if (ct < nct || wave == 3) {
            int c = (ctb + ct)*16 + lm;
            #pragma unroll
            for (int rg = 0; rg < 2; rg++) {
                #pragma unroll
                for (int r = 0; r < 4; r++) {
                    int nl = rg*16 + lq*4 + r;
                    float v = (ct < nct) ? acc[ct][rg][r] : 0.f;
                    partial[((long)(nb0+nl)*KSPLIT_ + kz)*PSTR_ + c] = v;
                }
            }
        }
    }
}

// ---------------- fused: r1 streaming reduce + r2/r3 LSE + final projection ----------------
__global__ void r23out_kernel(const float* __restrict__ partial, const void* __restrict__ b_rel,
                              const float* __restrict__ mu, const float* __restrict__ c23p,
                              const int* __restrict__ hts, const int* __restrict__ mention_idx,
                              const float* __restrict__ W_bilF, const void* __restrict__ b_bil,
                              void* __restrict__ out, const void* __restrict__ seqd) {
    int bp = blockIdx.x;
    int b = bp >> 8;
    int c = threadIdx.x;
    int isbf = detect_bf(seqd);
    __shared__ float row[292];
    if (c < C_) {
        const float* pr = partial + (long)bp*KSPLIT_*PSTR_;
        float r1v = 0.f;
        #pragma unroll 8
        for (int kz = 0; kz < KSPLIT_; kz++)
            r1v += pr[kz*PSTR_ + c];
        r1v += ldIn(b_rel, c, isbf);
        int h_e = hts[bp*2+0], t_e = hts[bp*2+1];
        const float* mu2h = mu;
        const float* mu2t = mu + 32768;
        const float* mu3h = mu + 65536;
        const float* mu3t = mu + 98304;
        float ah2[4], at2[4], ah3[4], at3[4];
        for (int m = 0; m < 4; m++) {
            int emh = mention_idx[(b*E_ + h_e)*M_ + m];
            int emt = mention_idx[(b*E_ + t_e)*M_ + m];
            ah2[m] = mu2h[(long)(b*128 + emh)*128 + c];
            ah3[m] = mu3h[(long)(b*128 + emh)*128 + c];
            at2[m] = mu2t[(long)(b*128 + emt)*128 + c];
            at3[m] = mu3t[(long)(b*128 + emt)*128 + c];
        }
        float c2 = 0.f, c3 = 0.f;
        #pragma unroll
        for (int j = 0; j < 16; j++) {
            c2 += c23p[j*194 + c];
            c3 += c23p[j*194 + 97 + c];
        }
        float v2[16], v3[16];
        int q = 0;
        for (int i = 0; i < 4; i++) {
            for (int j = 0; j < 4; j++, q++) {
                float x2 = ah2[i] + at2[j] + c2;
                v2[q] = tanhf(x2);
                float x3 = ah3[i] + at3[j] + c3;
                float t = tanhf(0.7978845608028654f * (x3 + 0.044715f*x3*x3*x3));
                v3[q] = 0.5f * x3 * (1.0f + t);
            }
        }
        float m2 = v2[0], m3 = v3[0];
        for (q = 1; q < 16; q++) { m2 = fmaxf(m2, v2[q]); m3 = fmaxf(m3, v3[q]); }
        float s2 = 0.f, s3 = 0.f;
        for (q = 0; q < 16; q++) { s2 += expf(v2[q]-m2); s3 += expf(v3[q]-m3); }
        row[c]        = r1v;
        row[C_ + c]   = m2 + logf(s2);
        row[2*C_ + c] = m3 + logf(s3);
    }
    __syncthreads();
    if (c >= C_) return;
    float a0 = 0.f, a1 = 0.f, a2 = 0.f, a3 = 0.f;
    #pragma unroll 4
    for (int k = 0; k < 288; k += 4) {
        a0 += row[k+0] * W_bilF[(k+0)*C_ + c];
        a1 += row[k+1] * W_bilF[(k+1)*C_ + c];
        a2 += row[k+2] * W_bilF[(k+2)*C_ + c];
        a3 += row[k+3] * W_bilF[(k+3)*C_ + c];
    }
    a0 += row[288] * W_bilF[288*C_ + c];
    a1 += row[289] * W_bilF[289*C_ + c];
    a2 += row[290] * W_bilF[290*C_ + c];
    float v = a0 + a1 + a2 + a3 + ldIn(b_bil, c, isbf);
    if (isbf) ((bf16*)out)[(long)bp*C_ + c] = (bf16)v;
    else      ((float*)out)[(long)bp*C_ + c] = v;
}

extern "C" void kernel_launch(void* const* d_in, const int* in_sizes, int n_in,
                              void* d_out, int out_size, void* d_ws, size_t ws_size,
                              hipStream_t stream) {
    const void* seq        = d_in[0];
    const void* attn       = d_in[1];
    const int*  entity_pos = (const int*)d_in[2];
    const int*  hts        = (const int*)d_in[3];
    const int*  mention_idx= (const int*)d_in[4];
    const void* W_head     = d_in[5];
    const void* b_head     = d_in[6];
    const void* W_tail     = d_in[7];
    const void* b_tail     = d_in[8];
    const void* W_rel      = d_in[9];
    const void* b_rel      = d_in[10];
    const void* W_fh       = d_in[11];
    const void* W_ft       = d_in[12];
    const void* b_f        = d_in[13];
    const void* W_unet     = d_in[14];
    const void* b_unet     = d_in[15];
    const void* W_mlp      = d_in[16];
    const void* b_mlp      = d_in[17];
    const void* W_bil      = d_in[18];
    const void* b_bil      = d_in[19];

    float* w = (float*)d_ws;
    unsigned short* mentb = (unsigned short*)(w + 64);       // 98304 fl
    float* ent_emb  = w + 98368;                             // 49152
    unsigned short* htb = (unsigned short*)(w + 540736);     // 131072 fl
    float* rs       = w + 671808;                            // 393216
    float* hz       = w + 1065024;                           // 393216
    float* tz       = w + 1458240;                           // 393216
    float* mu       = w + 1851456;                           // 131072
    unsigned short* seqT  = (unsigned short*)(w + 1982784);  // 393216 fl
    unsigned short* WhT   = (unsigned short*)(w + 2376000);  // 589824 fl
    unsigned short* WtT   = (unsigned short*)(w + 2965824);  // 589824 fl
    unsigned short* WfhT  = (unsigned short*)(w + 3555648);  // 294912 fl
    unsigned short* WftT  = (unsigned short*)(w + 3850560);  // 294912 fl
    unsigned short* WunetT= (unsigned short*)(w + 4145472);  // 49152 fl
    unsigned short* WmlpT = (unsigned short*)(w + 4194624);  // 49152 fl
    unsigned short* Tbh   = (unsigned short*)(w + 4243776);  // 98304 fl
    unsigned short* Tbt   = (unsigned short*)(w + 4342080);  // 98304 fl
    unsigned short* WBt   = (unsigned short*)(w + 5226816);  // 2752512 fl (fragment-major tiles)
    float* partial  = w + 7979328;                           // used: 512*48*128 = 3145728
    float* c23p     = w + 11200000;                          // 3104 fl (in partial slot's tail)
    float* W_bilF   = w + 11649344;                          // 28227 fl

    // 1. prep+ghatt: c23 (z=0) + W_rel conv (z=1) + transposes (z=2..9)
    //    + W_bilF (z=10) + ghatt (z=11, overlapped)
    {
        PrepArgs a = {};
        const void* srcs[8] = {W_head, W_tail, W_fh, W_ft, W_unet, W_mlp, seq, seq};
        long offs[8]   = {0,0,0,0,0,0,0,393216};
        int Ks[8]      = {1536,1536,768,768,768,768,512,512};
        int Ncols8[8]  = {768,768,768,768,97,97,768,768};
        int Npads[8]   = {768,768,768,768,128,128,768,768};
        unsigned short* dsts[8] = {WhT, WtT, WfhT, WftT, WunetT, WmlpT, seqT, seqT+393216};
        for (int z = 0; z < 8; z++) {
            a.src[z]=srcs[z]; a.off[z]=offs[z]; a.K[z]=Ks[z];
            a.Ncols[z]=Ncols8[z]; a.Npad[z]=Npads[z]; a.dst[z]=dsts[z];
        }
        a.W_bil = W_bil; a.W_bilF = W_bilF;
        a.b_f = b_f; a.W_unet = W_unet; a.b_unet = b_unet;
        a.W_mlp = W_mlp; a.b_mlp = b_mlp; a.c23p = c23p;
        a.W_rel = W_rel; a.WBt = WBt;
        a.seqd = seq;
        a.attn = attn; a.entity_pos = entity_pos; a.hts = hts;
        a.mentb = mentb; a.ent_emb = ent_emb; a.htb = htb;
        prep_kernel<<<dim3(48, 16, 12), 256, 0, stream>>>(a);
    }
    // 2. gemmA: rs (z=0,1) + T_{h,t} (z=2,3)
    {
        MfmaJob ga = {};
        ga.seqd = seq; ga.hts = hts; ga.ent_emb = ent_emb; ga.rsrc = rs;
        for (int z = 0; z < 2; z++) {
            ga.A[z] = htb + (long)z*256*512; ga.Bt[z] = seqT + (long)z*393216;
            ga.bias[z] = nullptr; ga.C[z] = rs + (long)z*256*768;
            ga.K[z] = 512; ga.ldc[z] = 768; ga.act[z] = 0; ga.obf[z] = 0;
            ga.Mt[z] = 256; ga.Nt[z] = 768; ga.gath[z] = 0;
        }
        ga.A[2] = mentb; ga.Bt[2] = WfhT; ga.bias[2] = nullptr; ga.C[2] = Tbh;
        ga.K[2] = 768; ga.ldc[2] = 768; ga.act[2] = 0; ga.obf[2] = 1;
        ga.Mt[2] = 256; ga.Nt[2] = 768; ga.gath[2] = 0;
        ga.A[3] = mentb; ga.Bt[3] = WftT; ga.bias[3] = nullptr; ga.C[3] = Tbt;
        ga.K[3] = 768; ga.ldc[3] = 768; ga.act[3] = 0; ga.obf[3] = 1;
        ga.Mt[3] = 256; ga.Nt[3] = 768; ga.gath[3] = 0;
        mfma_nt2_kernel<<<dim3(8, 24, 4), 256, 0, stream>>>(ga);
    }
    // 3. gemmBC: hz/tz (z=0,1, A gathered = catb fused) + mu (z=2..5)
    {
        MfmaJob ga = {};
        ga.seqd = seq; ga.hts = hts; ga.ent_emb = ent_emb; ga.rsrc = rs;
        ga.A[0] = nullptr; ga.Bt[0] = WhT; ga.bias[0] = b_head; ga.C[0] = hz;
        ga.A[1] = nullptr; ga.Bt[1] = WtT; ga.bias[1] = b_tail; ga.C[1] = tz;
        for (int z = 0; z < 2; z++) {
            ga.K[z] = 1536; ga.ldc[z] = 768; ga.act[z] = 1; ga.obf[z] = 0;
            ga.Mt[z] = 512; ga.Nt[z] = 768; ga.gath[z] = z + 1;
        }
        const unsigned short* As[4] = {Tbh, Tbt, Tbh, Tbt};
        const unsigned short* Bs[4] = {WunetT, WunetT, WmlpT, WmlpT};
        for (int q = 0; q < 4; q++) {
            int z = 2 + q;
            ga.A[z] = As[q]; ga.Bt[z] = Bs[q]; ga.bias[z] = nullptr;
            ga.C[z] = mu + q*32768;
            ga.K[z] = 768; ga.ldc[z] = 128; ga.act[z] = 0; ga.obf[z] = 0;
            ga.Mt[z] = 256; ga.Nt[z] = 128; ga.gath[z] = 0;
        }
        mfma_nt2_kernel<<<dim3(16, 24, 6), 256, 0, stream>>>(ga);
    }
    // 4. r1 partials via MFMA (v8: fragment-major, barrier-free)
    r1_mfma_kernel<<<dim3(KSPLIT_, 16), 256, 0, stream>>>(hz, tz, WBt, partial);
    // 5. fused reduce + r2/r3 + final projection
    r23out_kernel<<<N_, 128, 0, stream>>>(partial, b_rel, mu, c23p, hts, mention_idx,
                                          W_bilF, b_bil, d_out, seq);
}

// Round 13
// 200.164 us; speedup vs baseline: 1.2192x; 1.0394x over previous
//
#include <hip/hip_runtime.h>
#include <hip/hip_bf16.h>

// Problem constants
#define B_  2
#define L_  512
#define D_  768
#define H_  12
#define E_  32
#define M_  4
#define P_  256
#define EMB_ 768
#define BS_ 64
#define C_  97
#define N_  (B_*P_)   // 512

#define KTOT_    49152      // EMB*BS
#define CPAD_    112        // 97 padded to 7*16
#define KSPLIT_  48
#define KCHUNK_  (KTOT_/KSPLIT_)   // 1024, 16 ks-steps of 64
#define PSTR_    128        // partial chunk stride (floats): 512 B, cache-line exclusive
#define TILE_    (CPAD_*64) // 7168 ushorts = 14336 B per k-step tile of WBt (fragment-major)

typedef __hip_bfloat16 bf16;
typedef __attribute__((ext_vector_type(8))) short bf16x8;
typedef __attribute__((ext_vector_type(4))) float f32x4;
typedef __attribute__((ext_vector_type(8))) float f32x8;

__device__ inline float ldIn(const void* p, long idx, int isbf) {
    return isbf ? (float)((const bf16*)p)[idx] : ((const float*)p)[idx];
}

__device__ inline unsigned short f2bf(float f) {
    bf16 h = (bf16)f;
    return *(unsigned short*)&h;
}

__device__ inline void cvt16(unsigned short* o, float4 a, float4 b, float4 c, float4 d) {
    o[0]=f2bf(a.x);  o[1]=f2bf(a.y);  o[2]=f2bf(a.z);  o[3]=f2bf(a.w);
    o[4]=f2bf(b.x);  o[5]=f2bf(b.y);  o[6]=f2bf(b.z);  o[7]=f2bf(b.w);
    o[8]=f2bf(c.x);  o[9]=f2bf(c.y);  o[10]=f2bf(c.z); o[11]=f2bf(c.w);
    o[12]=f2bf(d.x); o[13]=f2bf(d.y); o[14]=f2bf(d.z); o[15]=f2bf(d.w);
}

// Per-wave inline dtype detection. bf16 N(0,1) never has (u>>7)&0xFF >= 140;
// fp32 low-halves are ~uniform -> ~45% hit rate; P(false bf16) ~ 5e-9.
__device__ inline int detect_bf(const void* seqd) {
    const unsigned short* u = (const unsigned short*)seqd;
    int lane = threadIdx.x & 63;
    unsigned short e = (u[lane] >> 7) & 0xFF;
    unsigned long long m = __ballot(e >= 140);
    return m == 0ull;
}

// ---------------- prep: z=0 {c23 partials, ment gather}, z=1 W_rel conv,
// z=2..9 transposes (vectorized), z=10 W_bil->f32, z=11 ent_att.
// Round-13 fix: z=11 computes ent_att ONCE per (b,e,h) — round 9-12's merged
// ghatt re-read each attn row ~16x from L2 (96 rows per pair-block x 512
// blocks vs 3072 distinct rows). Pair products move to a tiny htatt launch.
struct PrepArgs {
    const void* src[8];
    long off[8];
    int K[8];
    int Ncols[8];
    int Npad[8];
    unsigned short* dst[8];
    const void* W_bil;  float* W_bilF;
    const void* b_f; const void* W_unet; const void* b_unet;
    const void* W_mlp; const void* b_mlp; float* c23p;
    const void* W_rel; unsigned short* WBt;
    const void* seqd;
    const void* attn; const int* entity_pos;
    unsigned short* mentb; float* ent_emb; float* ent_att;
};

union PrepSm {
    float T[32][65];                 // 8320 B
    unsigned short TW[CPAD_][80];    // 17920 B
};

__global__ void prep_kernel(PrepArgs a) {
    int isbf = detect_bf(a.seqd);
    int z = blockIdx.z;
    __shared__ PrepSm sm;
    int tid = threadIdx.x;
    if (z == 0) {
        int lin = blockIdx.y*48 + blockIdx.x;
        if (lin < 16) {
            // c23 partials: 16 blocks x 48 d-rows -> c23p[lin][2][97]
            int c = tid;
            if (c >= C_) return;
            float s2 = 0.f, s3 = 0.f;
            int d0 = lin*48;
            for (int i = 0; i < 48; i++) {
                int d = d0 + i;
                float bf = ldIn(a.b_f, d, isbf);
                s2 += bf * ldIn(a.W_unet, (long)d*C_ + c, isbf);
                s3 += bf * ldIn(a.W_mlp,  (long)d*C_ + c, isbf);
            }
            if (lin == 0) {
                s2 += ldIn(a.b_unet, c, isbf);
                s3 += ldIn(a.b_mlp,  c, isbf);
            }
            a.c23p[lin*194 + c]      = s2;
            a.c23p[lin*194 + 97 + c] = s3;
        } else if (lin >= 64 && lin < 128) {
            // ment gather + ent_emb logsumexp (64 blocks)
            int be = lin - 64;
            int b = be >> 5;
            int pos[M_];
            for (int m = 0; m < M_; m++) pos[m] = a.entity_pos[be*M_+m] + 1;
            for (int d = tid; d < D_; d += 256) {
                float x[M_];
                for (int m = 0; m < M_; m++) {
                    x[m] = ldIn(a.seqd, ((long)b*L_ + pos[m])*D_ + d, isbf);
                    a.mentb[((long)be*M_ + m)*D_ + d] = f2bf(x[m]);
                }
                float mx = fmaxf(fmaxf(x[0],x[1]), fmaxf(x[2],x[3]));
                float s = expf(x[0]-mx)+expf(x[1]-mx)+expf(x[2]-mx)+expf(x[3]-mx);
                a.ent_emb[(long)be*D_ + d] = mx + logf(s);
            }
        }
    } else if (z == 1) {
        // W_rel -> WBt FRAGMENT-MAJOR: per k-step tile t, item idx=(ct*2+h)*64+l
        int lin = blockIdx.y*48 + blockIdx.x;
        if (lin >= KTOT_/64) return;
        int k0 = lin * 64;
        for (int idx = tid; idx < 64*97; idx += 256) {
            int kk = idx / 97, c = idx % 97;
            sm.TW[c][kk] = f2bf(ldIn(a.W_rel, (long)(k0+kk)*C_ + c, isbf));
        }
        for (int idx = tid; idx < 15*64; idx += 256) {
            sm.TW[97 + (idx>>6)][idx & 63] = 0;
        }
        __syncthreads();
        unsigned short* tb = a.WBt + (long)lin*TILE_;
        for (int t = 0; t < 4; t++) {
            int idx = tid + t*256;      // < 896
            if (idx < 896) {
                int l  = idx & 63;
                int h  = (idx >> 6) & 1;
                int ct = idx >> 7;
                int row = ct*16 + (l & 15);
                int col = h*32 + (l >> 4)*8;
                *(uint4*)(tb + idx*8) = *(uint4*)&sm.TW[row][col];
            }
        }
    } else if (z <= 9) {
        int j = z - 2;
        int K = a.K[j], Ncols = a.Ncols[j], Npad = a.Npad[j];
        int k0 = blockIdx.x*32, n0 = blockIdx.y*64;
        if (k0 >= K || n0 >= Npad) return;
        const void* src = a.src[j];
        long off = a.off[j];
        unsigned short* dst = a.dst[j];
        // read: 32x64 tile, 8 consecutive cols per thread (vector when aligned)
        int r = tid >> 3, c8 = (tid & 7) * 8;
        if ((Ncols & 7) == 0) {
            long base = off + (long)(k0+r)*Ncols + n0 + c8;
            if (isbf) {
                unsigned short tmp[8];
                *(uint4*)tmp = *(const uint4*)((const unsigned short*)src + base);
                #pragma unroll
                for (int e = 0; e < 8; e++) {
                    bf16 hh = *(bf16*)&tmp[e];
                    sm.T[r][c8+e] = (float)hh;
                }
            } else {
                const float* sp = (const float*)src + base;
                float4 x = *(const float4*)sp;
                float4 y = *(const float4*)(sp + 4);
                sm.T[r][c8+0]=x.x; sm.T[r][c8+1]=x.y; sm.T[r][c8+2]=x.z; sm.T[r][c8+3]=x.w;
                sm.T[r][c8+4]=y.x; sm.T[r][c8+5]=y.y; sm.T[r][c8+6]=y.z; sm.T[r][c8+7]=y.w;
            }
        } else {
            #pragma unroll
            for (int e = 0; e < 8; e++) {
                int n = n0 + c8 + e;
                sm.T[r][c8+e] = (n < Ncols) ? ldIn(src, off + (long)(k0+r)*Ncols + n, isbf) : 0.f;
            }
        }
        __syncthreads();
        // write: thread handles row n0+nn, k-range k0+q8..+7 as one uint4
        int nn = tid >> 2, q8 = (tid & 3) * 8;
        unsigned short o[8];
        #pragma unroll
        for (int e = 0; e < 8; e++) o[e] = f2bf(sm.T[q8+e][nn]);
        *(uint4*)(dst + (long)(n0+nn)*K + k0 + q8) = *(uint4*)o;
    } else if (z == 10) {
        int lin = blockIdx.y*48 + blockIdx.x;
        int idx = lin*256 + tid;
        if (idx < 291*C_) a.W_bilF[idx] = ldIn(a.W_bil, idx, isbf);
    } else {
        // z=11: ent_att[beh][l] = 0.25 * sum_m attn[b,h,pos[m],l]
        // 768 blocks, attn read exactly once per needed row, coalesced.
        int beh = blockIdx.y*48 + blockIdx.x;
        if (beh >= 768) return;
        int h = beh % H_;
        int be = beh / H_;
        int b = be >> 5;
        int pos[M_];
        for (int m = 0; m < M_; m++) pos[m] = a.entity_pos[be*M_+m] + 1;
        for (int t = 0; t < 2; t++) {
            int l = tid + t*256;
            float s = 0.f;
            for (int m = 0; m < M_; m++)
                s += ldIn(a.attn, (((long)(b*H_ + h))*L_ + pos[m])*L_ + l, isbf);
            a.ent_att[(long)beh*L_ + l] = 0.25f * s;
        }
    }
}

// ---------------- htatt: ht_att (bf16) = normalize_L( mean_H(ea_h*ea_t) ) ----
// Reads the 1.5 MB ent_att (L2-resident), 24 rows per block.
__global__ void htatt_kernel(const float* __restrict__ ent_att, const int* __restrict__ hts,
                             unsigned short* __restrict__ htb) {
    int bp = blockIdx.x;            // 512 blocks
    int b = bp >> 8;
    int h_e = hts[bp*2+0], t_e = hts[bp*2+1];
    const float* ea_h = ent_att + (long)((b*E_ + h_e)*H_)*L_;
    const float* ea_t = ent_att + (long)((b*E_ + t_e)*H_)*L_;
    __shared__ float red[256];
    float v[2];
    for (int t = 0; t < 2; t++) {
        int l = threadIdx.x + t*256;
        float s = 0.f;
        for (int h = 0; h < H_; h++) s += ea_h[h*L_+l] * ea_t[h*L_+l];
        v[t] = s * (1.0f/H_);
    }
    red[threadIdx.x] = v[0] + v[1];
    __syncthreads();
    for (int off = 128; off > 0; off >>= 1) {
        if (threadIdx.x < off) red[threadIdx.x] += red[threadIdx.x+off];
        __syncthreads();
    }
    float inv = 1.0f / (red[0] + 1e-5f);
    for (int t = 0; t < 2; t++) {
        int l = threadIdx.x + t*256;
        htb[(long)bp*L_ + l] = f2bf(v[t] * inv);
    }
}

// ---------------- Generic MFMA GEMM, 32x32 tiles, BK=128 ----------------
// gath[z] != 0: A-operand gathered on the fly (catb fused): rows are
// ent_emb[b][hts[m]] for k<768 and rs[m] for k>=768.
struct MfmaJob {
    const unsigned short* A[8];
    const unsigned short* Bt[8];
    const void* bias[8];
    void* C[8];
    const void* seqd;
    const int* hts;
    const float* ent_emb;
    const float* rsrc;
    int K[8];
    int ldc[8];
    int act[8];
    int obf[8];
    int Mt[8];
    int Nt[8];
    int gath[8];   // 0 none, 1 gather h, 2 gather t
};

__global__ void mfma_nt2_kernel(MfmaJob args) {
    int z = blockIdx.z;
    int m0 = blockIdx.x*32, n0 = blockIdx.y*32;
    if (m0 >= args.Mt[z] || n0 >= args.Nt[z]) return;
    int isbf = detect_bf(args.seqd);
    const unsigned short* A  = args.A[z];
    const unsigned short* Bt = args.Bt[z];
    const void* bias = args.bias[z];
    void* C = args.C[z];
    int K = args.K[z], ldc = args.ldc[z], act = args.act[z], obf = args.obf[z];
    int gmode = args.gath[z];
    __shared__ unsigned short Al[2][32][136];
    __shared__ unsigned short Btl[2][32][136];
    int tid = threadIdx.x, wave = tid>>6, lane = tid&63;
    int lm = lane&15, lq = lane>>4;
    int rowg = wave>>1, cgrp = wave&1;   // wave -> (row half, col half)
    int rr = tid >> 3;                // 0..31
    int kc = (tid & 7) * 16;          // col offset in elements (128 cols/stage)
    const float *gh = nullptr, *gr = nullptr;
    if (gmode) {
        int m = m0 + rr, b = m >> 8;
        int ent = args.hts[m*2 + (gmode-1)];
        gh = args.ent_emb + (long)(b*E_ + ent)*D_ + kc;
        gr = args.rsrc + (long)m*EMB_ + kc;
    }
    uint4 ra0, ra1, rb0, rb1;
    float4 fa0, fa1, fa2, fa3;

    if (gmode) {
        fa0 = *(const float4*)gh;      fa1 = *(const float4*)(gh+4);
        fa2 = *(const float4*)(gh+8);  fa3 = *(const float4*)(gh+12);
        unsigned short o[16];
        cvt16(o, fa0, fa1, fa2, fa3);
        *(uint4*)&Al[0][rr][kc]   = *(uint4*)o;
        *(uint4*)&Al[0][rr][kc+8] = *(uint4*)(o+8);
    } else {
        ra0 = *(const uint4*)(A + (long)(m0+rr)*K + kc);
        ra1 = *(const uint4*)(A + (long)(m0+rr)*K + kc + 8);
        *(uint4*)&Al[0][rr][kc]   = ra0;
        *(uint4*)&Al[0][rr][kc+8] = ra1;
    }
    rb0 = *(const uint4*)(Bt + (long)(n0+rr)*K + kc);
    rb1 = *(const uint4*)(Bt + (long)(n0+rr)*K + kc + 8);
    *(uint4*)&Btl[0][rr][kc]   = rb0;
    *(uint4*)&Btl[0][rr][kc+8] = rb1;

    int nst = K >> 7;                 // K in {512,768,1536}, all mult of 128
    f32x4 acc = {};
    for (int ks = 0; ks < nst; ks++) {
        __syncthreads();
        if (ks+1 < nst) {
            int kk = (ks+1) << 7;
            if (gmode) {
                const float* s = (kk < D_) ? (gh + kk) : (gr + kk - D_);
                fa0 = *(const float4*)s;      fa1 = *(const float4*)(s+4);
                fa2 = *(const float4*)(s+8);  fa3 = *(const float4*)(s+12);
            } else {
                ra0 = *(const uint4*)(A + (long)(m0+rr)*K + kk + kc);
                ra1 = *(const uint4*)(A + (long)(m0+rr)*K + kk + kc + 8);
            }
            rb0 = *(const uint4*)(Bt + (long)(n0+rr)*K + kk + kc);
            rb1 = *(const uint4*)(Bt + (long)(n0+rr)*K + kk + kc + 8);
        }
        int cb = ks & 1;
        #pragma unroll
        for (int half = 0; half < 4; half++) {
            bf16x8 af  = *(bf16x8*)&Al[cb][rowg*16+lm][half*32+lq*8];
            bf16x8 bfr = *(bf16x8*)&Btl[cb][cgrp*16+lm][half*32+lq*8];
            acc = __builtin_amdgcn_mfma_f32_16x16x32_bf16(af, bfr, acc, 0, 0, 0);
        }
        if (ks+1 < nst) {
            int nb = (ks+1) & 1;
            if (gmode) {
                unsigned short o[16];
                cvt16(o, fa0, fa1, fa2, fa3);
                *(uint4*)&Al[nb][rr][kc]   = *(uint4*)o;
                *(uint4*)&Al[nb][rr][kc+8] = *(uint4*)(o+8);
            } else {
                *(uint4*)&Al[nb][rr][kc]   = ra0;
                *(uint4*)&Al[nb][rr][kc+8] = ra1;
            }
            *(uint4*)&Btl[nb][rr][kc]   = rb0;
            *(uint4*)&Btl[nb][rr][kc+8] = rb1;
        }
    }
    int n = n0 + cgrp*16 + lm;
    float bia = bias ? ldIn(bias, n, isbf) : 0.f;
    #pragma unroll
    for (int r = 0; r < 4; r++) {
        int m = m0 + rowg*16 + lq*4 + r;
        float v = acc[r] + bia;
        if (act == 1) v = tanhf(v);
        if (obf) ((unsigned short*)C)[(long)m*ldc + n] = f2bf(v);
        else     ((float*)C)[(long)m*ldc + n] = v;
    }
}

// ================= r1 via MFMA (v8, unchanged) =================
__global__ __launch_bounds__(256, 3)
void r1_mfma_kernel(const float* __restrict__ hz, const float* __restrict__ tz,
                    const unsigned short* __restrict__ WBt,
                    float* __restrict__ partial) {
    __shared__ float hzL[32][17];
    int kz = blockIdx.x;
    int nb0 = blockIdx.y * 32;
    int gk0 = kz * 16;               // global k-step base
    int gi0 = kz * 16;               // hz col base
    int g0 = (kz * KCHUNK_) >> 12;   // tz group, fixed for the whole chunk
    int tid = threadIdx.x;
    int wave = tid >> 6, lane = tid & 63;
    int lm = lane & 15;
    int ctb = wave * 2;              // c-tile base: 0,2,4,6
    int nct = (wave < 3) ? 2 : 1;    // c-tiles this wave computes

    {
        int r = tid >> 3, q = (tid & 7) * 2;
        float2 v = *(const float2*)(hz + (long)(nb0 + r)*EMB_ + gi0 + q);
        hzL[r][q] = v.x; hzL[r][q+1] = v.y;
    }
    int lq = lane >> 4;
    f32x8 tza[2], tzb[2];            // [rowg], halves 0/1
    #pragma unroll
    for (int rg = 0; rg < 2; rg++) {
        const float* tp = tz + (long)(nb0 + rg*16 + lm)*EMB_ + g0*64;
        float4 x0 = *(const float4*)(tp + lq*8);
        float4 y0 = *(const float4*)(tp + lq*8 + 4);
        float4 x1 = *(const float4*)(tp + 32 + lq*8);
        float4 y1 = *(const float4*)(tp + 32 + lq*8 + 4);
        tza[rg][0]=x0.x; tza[rg][1]=x0.y; tza[rg][2]=x0.z; tza[rg][3]=x0.w;
        tza[rg][4]=y0.x; tza[rg][5]=y0.y; tza[rg][6]=y0.z; tza[rg][7]=y0.w;
        tzb[rg][0]=x1.x; tzb[rg][1]=x1.y; tzb[rg][2]=x1.z; tzb[rg][3]=x1.w;
        tzb[rg][4]=y1.x; tzb[rg][5]=y1.y; tzb[rg][6]=y1.z; tzb[rg][7]=y1.w;
    }
    __syncthreads();   // hzL ready; ONLY barrier in the kernel

    const unsigned short* wb = WBt + (long)gk0*TILE_ + lane*8;

    f32x4 acc[2][2] = {};            // [ct][rowg]
    bf16x8 cb[2][2];                 // [ct][h] current B-frags
    #pragma unroll
    for (int ct = 0; ct < 2; ct++)
        if (ct < nct)
            #pragma unroll
            for (int h = 0; h < 2; h++)
                cb[ct][h] = *(const bf16x8*)(wb + ((ctb+ct)*2 + h)*512);

    #pragma unroll 2
    for (int ks = 0; ks < KCHUNK_/64; ks++) {
        bf16x8 nbuf[2][2];
        if (ks+1 < KCHUNK_/64) {
            const unsigned short* wn = wb + (long)(ks+1)*TILE_;
            #pragma unroll
            for (int ct = 0; ct < 2; ct++)
                if (ct < nct)
                    #pragma unroll
                    for (int h = 0; h < 2; h++)
                        nbuf[ct][h] = *(const bf16x8*)(wn + ((ctb+ct)*2 + h)*512);
        }
        float hv0 = hzL[lm][ks];
        float hv1 = hzL[16 + lm][ks];
        unsigned short o00[8], o01[8], o10[8], o11[8];
        #pragma unroll
        for (int e = 0; e < 8; e++) {
            o00[e] = f2bf(tza[0][e] * hv0);
            o01[e] = f2bf(tzb[0][e] * hv0);
            o10[e] = f2bf(tza[1][e] * hv1);
            o11[e] = f2bf(tzb[1][e] * hv1);
        }
        bf16x8 a00 = *(bf16x8*)o00, a01 = *(bf16x8*)o01;
        bf16x8 a10 = *(bf16x8*)o10, a11 = *(bf16x8*)o11;
        #pragma unroll
        for (int ct = 0; ct < 2; ct++) {
            if (ct < nct) {
                acc[ct][0] = __builtin_amdgcn_mfma_f32_16x16x32_bf16(a00, cb[ct][0], acc[ct][0], 0, 0, 0);
                acc[ct][0] = __builtin_amdgcn_mfma_f32_16x16x32_bf16(a01, cb[ct][1], acc[ct][0], 0, 0, 0);
                acc[ct][1] = __builtin_amdgcn_mfma_f32_16x16x32_bf16(a10, cb[ct][0], acc[ct][1], 0, 0, 0);
                acc[ct][1] = __builtin_amdgcn_mfma_f32_16x16x32_bf16(a11, cb[ct][1], acc[ct][1], 0, 0, 0);
            }
        }
        if (ks+1 < KCHUNK_/64) {
            #pragma unroll
            for (int ct = 0; ct < 2; ct++)
                if (ct < nct)
                    #pragma unroll
                    for (int h = 0; h < 2; h++)
                        cb[ct][h] = nbuf[ct][h];
        }
    }
    #pragma unroll
    for (int ct = 0; ct < 2; ct++) {
        if (ct < nct || wave == 3) {
            int c = (ctb + ct)*16 + lm;
            #pragma unroll
            for (int rg = 0; rg < 2; rg++) {
                #pragma unroll
                for (int r = 0; r < 4; r++) {
                    int nl = rg*16 + lq*4 + r;
                    float v = (ct < nct) ? acc[ct][rg][r] : 0.f;
                    partial[((long)(nb0+nl)*KSPLIT_ + kz)*PSTR_ + c] = v;
                }
            }
        }
    }
}

// ---------------- fused: r1 streaming reduce + r2/r3 LSE + final projection ----------------
__global__ void r23out_kernel(const float* __restrict__ partial, const void* __restrict__ b_rel,
                              const float* __restrict__ mu, const float* __restrict__ c23p,
                              const int* __restrict__ hts, const int* __restrict__ mention_idx,
                              const float* __restrict__ W_bilF, const void* __restrict__ b_bil,
                              void* __restrict__ out, const void* __restrict__ seqd) {
    int bp = blockIdx.x;
    int b = bp >> 8;
    int c = threadIdx.x;
    int isbf = detect_bf(seqd);
    __shared__ float row[292];
    if (c < C_) {
        const float* pr = partial + (long)bp*KSPLIT_*PSTR_;
        float r1v = 0.f;
        #pragma unroll 8
        for (int kz = 0; kz < KSPLIT_; kz++)
            r1v += pr[kz*PSTR_ + c];
        r1v += ldIn(b_rel, c, isbf);
        int h_e = hts[bp*2+0], t_e = hts[bp*2+1];
        const float* mu2h = mu;
        const float* mu2t = mu + 32768;
        const float* mu3h = mu + 65536;
        const float* mu3t = mu + 98304;
        float ah2[4], at2[4], ah3[4], at3[4];
        for (int m = 0; m < 4; m++) {
            int emh = mention_idx[(b*E_ + h_e)*M_ + m];
            int emt = mention_idx[(b*E_ + t_e)*M_ + m];
            ah2[m] = mu2h[(long)(b*128 + emh)*128 + c];
            ah3[m] = mu3h[(long)(b*128 + emh)*128 + c];
            at2[m] = mu2t[(long)(b*128 + emt)*128 + c];
            at3[m] = mu3t[(long)(b*128 + emt)*128 + c];
        }
        float c2 = 0.f, c3 = 0.f;
        #pragma unroll
        for (int j = 0; j < 16; j++) {
            c2 += c23p[j*194 + c];
            c3 += c23p[j*194 + 97 + c];
        }
        float v2[16], v3[16];
        int q = 0;
        for (int i = 0; i < 4; i++) {
            for (int j = 0; j < 4; j++, q++) {
                float x2 = ah2[i] + at2[j] + c2;
                v2[q] = tanhf(x2);
                float x3 = ah3[i] + at3[j] + c3;
                float t = tanhf(0.7978845608028654f * (x3 + 0.044715f*x3*x3*x3));
                v3[q] = 0.5f * x3 * (1.0f + t);
            }
        }
        float m2 = v2[0], m3 = v3[0];
        for (q = 1; q < 16; q++) { m2 = fmaxf(m2, v2[q]); m3 = fmaxf(m3, v3[q]); }
        float s2 = 0.f, s3 = 0.f;
        for (q = 0; q < 16; q++) { s2 += expf(v2[q]-m2); s3 += expf(v3[q]-m3); }
        row[c]        = r1v;
        row[C_ + c]   = m2 + logf(s2);
        row[2*C_ + c] = m3 + logf(s3);
    }
    __syncthreads();
    if (c >= C_) return;
    float a0 = 0.f, a1 = 0.f, a2 = 0.f, a3 = 0.f;
    #pragma unroll 4
    for (int k = 0; k < 288; k += 4) {
        a0 += row[k+0] * W_bilF[(k+0)*C_ + c];
        a1 += row[k+1] * W_bilF[(k+1)*C_ + c];
        a2 += row[k+2] * W_bilF[(k+2)*C_ + c];
        a3 += row[k+3] * W_bilF[(k+3)*C_ + c];
    }
    a0 += row[288] * W_bilF[288*C_ + c];
    a1 += row[289] * W_bilF[289*C_ + c];
    a2 += row[290] * W_bilF[290*C_ + c];
    float v = a0 + a1 + a2 + a3 + ldIn(b_bil, c, isbf);
    if (isbf) ((bf16*)out)[(long)bp*C_ + c] = (bf16)v;
    else      ((float*)out)[(long)bp*C_ + c] = v;
}

extern "C" void kernel_launch(void* const* d_in, const int* in_sizes, int n_in,
                              void* d_out, int out_size, void* d_ws, size_t ws_size,
                              hipStream_t stream) {
    const void* seq        = d_in[0];
    const void* attn       = d_in[1];
    const int*  entity_pos = (const int*)d_in[2];
    const int*  hts        = (const int*)d_in[3];
    const int*  mention_idx= (const int*)d_in[4];
    const void* W_head     = d_in[5];
    const void* b_head     = d_in[6];
    const void* W_tail     = d_in[7];
    const void* b_tail     = d_in[8];
    const void* W_rel      = d_in[9];
    const void* b_rel      = d_in[10];
    const void* W_fh       = d_in[11];
    const void* W_ft       = d_in[12];
    const void* b_f        = d_in[13];
    const void* W_unet     = d_in[14];
    const void* b_unet     = d_in[15];
    const void* W_mlp      = d_in[16];
    const void* b_mlp      = d_in[17];
    const void* W_bil      = d_in[18];
    const void* b_bil      = d_in[19];

    float* w = (float*)d_ws;
    unsigned short* mentb = (unsigned short*)(w + 64);       // 98304 fl
    float* ent_emb  = w + 98368;                             // 49152
    float* ent_att  = w + 147520;                            // 393216
    unsigned short* htb = (unsigned short*)(w + 540736);     // 131072 fl
    float* rs       = w + 671808;                            // 393216
    float* hz       = w + 1065024;                           // 393216
    float* tz       = w + 1458240;                           // 393216
    float* mu       = w + 1851456;                           // 131072
    unsigned short* seqT  = (unsigned short*)(w + 1982784);  // 393216 fl
    unsigned short* WhT   = (unsigned short*)(w + 2376000);  // 589824 fl
    unsigned short* WtT   = (unsigned short*)(w + 2965824);  // 589824 fl
    unsigned short* WfhT  = (unsigned short*)(w + 3555648);  // 294912 fl
    unsigned short* WftT  = (unsigned short*)(w + 3850560);  // 294912 fl
    unsigned short* WunetT= (unsigned short*)(w + 4145472);  // 49152 fl
    unsigned short* WmlpT = (unsigned short*)(w + 4194624);  // 49152 fl
    unsigned short* Tbh   = (unsigned short*)(w + 4243776);  // 98304 fl
    unsigned short* Tbt   = (unsigned short*)(w + 4342080);  // 98304 fl
    unsigned short* WBt   = (unsigned short*)(w + 5226816);  // 2752512 fl (fragment-major tiles)
    float* partial  = w + 7979328;                           // used: 512*48*128 = 3145728
    float* c23p     = w + 11200000;                          // 3104 fl (in partial slot's tail)
    float* W_bilF   = w + 11649344;                          // 28227 fl

    // 1. prep: {c23, ment} (z=0) + W_rel conv (z=1) + transposes (z=2..9)
    //    + W_bilF (z=10) + ent_att (z=11)
    {
        PrepArgs a = {};
        const void* srcs[8] = {W_head, W_tail, W_fh, W_ft, W_unet, W_mlp, seq, seq};
        long offs[8]   = {0,0,0,0,0,0,0,393216};
        int Ks[8]      = {1536,1536,768,768,768,768,512,512};
        int Ncols8[8]  = {768,768,768,768,97,97,768,768};
        int Npads[8]   = {768,768,768,768,128,128,768,768};
        unsigned short* dsts[8] = {WhT, WtT, WfhT, WftT, WunetT, WmlpT, seqT, seqT+393216};
        for (int z = 0; z < 8; z++) {
            a.src[z]=srcs[z]; a.off[z]=offs[z]; a.K[z]=Ks[z];
            a.Ncols[z]=Ncols8[z]; a.Npad[z]=Npads[z]; a.dst[z]=dsts[z];
        }
        a.W_bil = W_bil; a.W_bilF = W_bilF;
        a.b_f = b_f; a.W_unet = W_unet; a.b_unet = b_unet;
        a.W_mlp = W_mlp; a.b_mlp = b_mlp; a.c23p = c23p;
        a.W_rel = W_rel; a.WBt = WBt;
        a.seqd = seq;
        a.attn = attn; a.entity_pos = entity_pos;
        a.mentb = mentb; a.ent_emb = ent_emb; a.ent_att = ent_att;
        prep_kernel<<<dim3(48, 16, 12), 256, 0, stream>>>(a);
    }
    // 2. htatt: pair products over L2-resident ent_att
    htatt_kernel<<<N_, 256, 0, stream>>>(ent_att, hts, htb);
    // 3. gemmA: rs (z=0,1) + T_{h,t} (z=2,3)
    {
        MfmaJob ga = {};
        ga.seqd = seq; ga.hts = hts; ga.ent_emb = ent_emb; ga.rsrc = rs;
        for (int z = 0; z < 2; z++) {
            ga.A[z] = htb + (long)z*256*512; ga.Bt[z] = seqT + (long)z*393216;
            ga.bias[z] = nullptr; ga.C[z] = rs + (long)z*256*768;
            ga.K[z] = 512; ga.ldc[z] = 768; ga.act[z] = 0; ga.obf[z] = 0;
            ga.Mt[z] = 256; ga.Nt[z] = 768; ga.gath[z] = 0;
        }
        ga.A[2] = mentb; ga.Bt[2] = WfhT; ga.bias[2] = nullptr; ga.C[2] = Tbh;
        ga.K[2] = 768; ga.ldc[2] = 768; ga.act[2] = 0; ga.obf[2] = 1;
        ga.Mt[2] = 256; ga.Nt[2] = 768; ga.gath[2] = 0;
        ga.A[3] = mentb; ga.Bt[3] = WftT; ga.bias[3] = nullptr; ga.C[3] = Tbt;
        ga.K[3] = 768; ga.ldc[3] = 768; ga.act[3] = 0; ga.obf[3] = 1;
        ga.Mt[3] = 256; ga.Nt[3] = 768; ga.gath[3] = 0;
        mfma_nt2_kernel<<<dim3(8, 24, 4), 256, 0, stream>>>(ga);
    }
    // 4. gemmBC: hz/tz (z=0,1, A gathered = catb fused) + mu (z=2..5)
    {
        MfmaJob ga = {};
        ga.seqd = seq; ga.hts = hts; ga.ent_emb = ent_emb; ga.rsrc = rs;
        ga.A[0] = nullptr; ga.Bt[0] = WhT; ga.bias[0] = b_head; ga.C[0] = hz;
        ga.A[1] = nullptr; ga.Bt[1] = WtT; ga.bias[1] = b_tail; ga.C[1] = tz;
        for (int z = 0; z < 2; z++) {
            ga.K[z] = 1536; ga.ldc[z] = 768; ga.act[z] = 1; ga.obf[z] = 0;
            ga.Mt[z] = 512; ga.Nt[z] = 768; ga.gath[z] = z + 1;
        }
        const unsigned short* As[4] = {Tbh, Tbt, Tbh, Tbt};
        const unsigned short* Bs[4] = {WunetT, WunetT, WmlpT, WmlpT};
        for (int q = 0; q < 4; q++) {
            int z = 2 + q;
            ga.A[z] = As[q]; ga.Bt[z] = Bs[q]; ga.bias[z] = nullptr;
            ga.C[z] = mu + q*32768;
            ga.K[z] = 768; ga.ldc[z] = 128; ga.act[z] = 0; ga.obf[z] = 0;
            ga.Mt[z] = 256; ga.Nt[z] = 128; ga.gath[z] = 0;
        }
        mfma_nt2_kernel<<<dim3(16, 24, 6), 256, 0, stream>>>(ga);
    }
    // 5. r1 partials via MFMA (v8: fragment-major, barrier-free)
    r1_mfma_kernel<<<dim3(KSPLIT_, 16), 256, 0, stream>>>(hz, tz, WBt, partial);
    // 6. fused reduce + r2/r3 + final projection
    r23out_kernel<<<N_, 128, 0, stream>>>(partial, b_rel, mu, c23p, hts, mention_idx,
                                          W_bilF, b_bil, d_out, seq);
}